// Round 12
// baseline (158.770 us; speedup 1.0000x reference)
//
#include <hip/hip_runtime.h>
#include <hip/hip_bf16.h>
#include <math.h>

// GNO collapsed: h = lift(x); per layer h = gelu(h@weff + beff),
//   weff = Wb + c0*(A@T' + qk su^T),  beff = bb + c0*(kq.T' + qbk su),
//   A = Wq@Wk^T, qk = Wq@bk, kq = Wk@bq, qbk = bq.bk     (G-INDEPENDENT)
//   T' = G@Wv + s bv^T,  su = Wv^T s + N bv,  G = h^T h, s = h^T 1,
//   c0 = (1/sqrt(64))/4096.
// Round 24: FINAL -- the r15/r22 champion, verbatim (92us dispatch,
// 157.3us bench, best of 12 measured variants).
// Session ledger (all regressed or null vs this):
//   r13 scattered atomicAdd reduce       220us (RMW + 2x write amp)
//   r16 global_load_lds + unpadded LDS   103us (4-way row conflicts)
//   r17 VGPR prefetch + Wk transpose     109us (serial-path growth)
//   r18/r19 NT=512 family                252us (128-VGPR scratch spill, 550MB)
//   r20/r21 h-side algebra swap          147us (conflicts 2x; no real shadow
//                                               under lockstep blocks)
//   r23 paired backoff polls             neutral bench / worse dispatch
//                                        (refutes poll-contention theory)
// Structural constraint: 8 global barrier rounds (2/layer) at 256-block
// scale cost ~7us each (skew + propagation, intrinsic) + ~36us minimized
// serial compute. Not HBM-bound (3%) nor VALU-bound (30%); alternatives
// that cut sync rounds pay more in data movement than they save.
// Structure: NT=256, 2 polls/layer, packed symmetric G-partials (2304 fl),
// wave-linear stc2 producer stores, all-block 18-float chunk combine,
// shadow-computed A/qk/kq/qbk, host-side dtype detect, s_sleep(2) polls.

#define NLAYER 4
#define NB 2
#define NN 4096
#define DD 64
#define RPB 32              // rows per block (8192 rows / 256 blocks)
#define NT 256
#define NBLK 256
#define SHP 68              // padded LDS row stride (floats)
#define C0F (1.0f/32768.0f)
#define PSZ 2304            // packed partial floats: 2176 tri + 64 s + 64 pad
#define NCH 128             // combine chunks per batch (= producers per batch)
#define CHW 18              // floats per combine chunk (128*18 = 2304)

typedef __hip_bfloat16 bf16;
typedef unsigned long long u64t;

__device__ __forceinline__ float b2f(const bf16 v) { return __bfloat162float(v); }

template <typename T> struct Acc;
template <> struct Acc<float> {
    static __device__ __forceinline__ float ld(const void* p, int i) { return ((const float*)p)[i]; }
    static __device__ __forceinline__ void st(void* p, int i, float v) { ((float*)p)[i] = v; }
};
template <> struct Acc<bf16> {
    static __device__ __forceinline__ float ld(const void* p, int i) { return b2f(((const bf16*)p)[i]); }
    static __device__ __forceinline__ void st(void* p, int i, float v) { ((bf16*)p)[i] = __float2bfloat16(v); }
};

__device__ __forceinline__ float gelu_exact(float x) {
    return 0.5f * x * (1.0f + erff(x * 0.70710678118654752f));
}

// ---- device-coherent helpers (agent scope, relaxed) ----
__device__ __forceinline__ float2 ldc2(const float* p) {
    u64t v = __hip_atomic_load((const u64t*)p, __ATOMIC_RELAXED, __HIP_MEMORY_SCOPE_AGENT);
    float2 r;
    r.x = __uint_as_float((unsigned)v);
    r.y = __uint_as_float((unsigned)(v >> 32));
    return r;
}
__device__ __forceinline__ void stc2(float* p, float a, float b) {
    u64t v = ((u64t)__float_as_uint(b) << 32) | (u64t)__float_as_uint(a);
    __hip_atomic_store((u64t*)p, v, __ATOMIC_RELAXED, __HIP_MEMORY_SCOPE_AGENT);
}
__device__ __forceinline__ unsigned ldw(unsigned* p) {
    return __hip_atomic_load(p, __ATOMIC_RELAXED, __HIP_MEMORY_SCOPE_AGENT);
}
__device__ __forceinline__ void stw(unsigned* p, unsigned v) {
    __hip_atomic_store(p, v, __ATOMIC_RELAXED, __HIP_MEMORY_SCOPE_AGENT);
}
// Poll epoch word until >= ep. Producer's __syncthreads (vmcnt(0) per wave)
// precedes its flag store, so flag-visibility implies data-visibility.
__device__ __forceinline__ void pollw(unsigned* p, unsigned ep) {
    int guard = 0;
    while (ldw(p) < ep && ++guard < (1 << 18)) __builtin_amdgcn_s_sleep(2);
}

// acc[a][b] += sum_k L[a].k * R[k].b   (NN product step)
__device__ __forceinline__ void mm4x4(float (&acc)[4][4],
    float4 L0, float4 L1, float4 L2, float4 L3,
    float4 R0, float4 R1, float4 R2, float4 R3)
{
    const float L[4][4] = {{L0.x,L0.y,L0.z,L0.w},{L1.x,L1.y,L1.z,L1.w},
                           {L2.x,L2.y,L2.z,L2.w},{L3.x,L3.y,L3.z,L3.w}};
    const float R[4][4] = {{R0.x,R0.y,R0.z,R0.w},{R1.x,R1.y,R1.z,R1.w},
                           {R2.x,R2.y,R2.z,R2.w},{R3.x,R3.y,R3.z,R3.w}};
    #pragma unroll
    for (int a = 0; a < 4; a++)
        #pragma unroll
        for (int k = 0; k < 4; k++)
            #pragma unroll
            for (int b = 0; b < 4; b++)
                acc[a][b] += L[a][k] * R[k][b];
}

// acc[a][b] += sum_k L[a].k * R[b].k   (NT product step: A = Wq @ Wk^T)
__device__ __forceinline__ void mmNT4x4(float (&acc)[4][4],
    float4 L0, float4 L1, float4 L2, float4 L3,
    float4 R0, float4 R1, float4 R2, float4 R3)
{
    const float L[4][4] = {{L0.x,L0.y,L0.z,L0.w},{L1.x,L1.y,L1.z,L1.w},
                           {L2.x,L2.y,L2.z,L2.w},{L3.x,L3.y,L3.z,L3.w}};
    const float R[4][4] = {{R0.x,R0.y,R0.z,R0.w},{R1.x,R1.y,R1.z,R1.w},
                           {R2.x,R2.y,R2.z,R2.w},{R3.x,R3.y,R3.z,R3.w}};
    #pragma unroll
    for (int a = 0; a < 4; a++)
        #pragma unroll
        for (int b = 0; b < 4; b++)
            #pragma unroll
            for (int k = 0; k < 4; k++)
                acc[a][b] += L[a][k] * R[b][k];
}

// acc[a][b] += A.a * B.b
__device__ __forceinline__ void outer4x4(float (&acc)[4][4], float4 A, float4 B)
{
    const float Aa[4] = {A.x, A.y, A.z, A.w};
    const float Ba[4] = {B.x, B.y, B.z, B.w};
    #pragma unroll
    for (int a = 0; a < 4; a++)
        #pragma unroll
        for (int b = 0; b < 4; b++)
            acc[a][b] += Aa[a] * Ba[b];
}

// LDS layout (floats):
//   sH  [32][68]  @ 0      resident h rows
//   B1  [64][68]  @ 2176   Wq -> Wv
//   B2  [64][68]  @ 6528   A (shadow-computed, persists through weff)
//   B3  [64][68]  @ 10880  partial-pack / combine-red / G / weff
//   B4  [64][68]  @ 15232  Wk -> Wb
//   B5  [64][68]  @ 19584  T'
//   smalls @ 23936..24511 ; red [4][64] @ 24512
// total 24768 floats = 99072 B -> 1 block/CU, 256 blocks co-resident.

#define SM_SS   23936
#define SM_SU   24000
#define SM_BK   24064
#define SM_BQ   24128
#define SM_BV   24192
#define SM_BE   24256
#define SM_QK   24320
#define SM_KQ   24384
#define SM_QBK  24448
#define SM_RED  24512
#define SM_TOT  24768

template <typename T>
__device__ void run_net(
    const void* x, const void* lw, const void* lb,
    const void* blkw, const void* blkb,
    const void* qw, const void* qb, const void* kw, const void* kb,
    const void* vw, const void* vb, const void* pw, const void* pb,
    void* out, float* Gpart, float* Gg,
    unsigned* aflag, unsigned* cflag,
    float* smem, int blk, int t)
{
    float (*sH)[SHP] = (float(*)[SHP])(smem);
    float (*B1)[SHP] = (float(*)[SHP])(smem + 2176);
    float (*B2)[SHP] = (float(*)[SHP])(smem + 6528);
    float (*B3)[SHP] = (float(*)[SHP])(smem + 10880);
    float (*B4)[SHP] = (float(*)[SHP])(smem + 15232);
    float (*B5)[SHP] = (float(*)[SHP])(smem + 19584);
    float* PS  = smem + 10880;          // packed-partial scratch (aliases B3)
    float* RED = smem + 10880;          // combine reduction [16][20] (aliases B3)
    float* sS  = smem + SM_SS;
    float* suS = smem + SM_SU;
    float* bkS = smem + SM_BK;
    float* bqS = smem + SM_BQ;
    float* bvS = smem + SM_BV;
    float* beS = smem + SM_BE;
    float* qkS = smem + SM_QK;
    float* kqS = smem + SM_KQ;
    float* qbkS = smem + SM_QBK;
    float (*red)[DD] = (float(*)[DD])(smem + SM_RED);

    const int row0 = blk * RPB;
    const int bb = blk >> 7;                      // batch of this block
    const int r = t >> 4, c4 = (t & 15) << 2;     // apply/lift mapping
    const int i4 = t >> 4, j4 = t & 15;           // 4x4 tile grid coords
    const int r0 = i4 << 2, c0 = j4 << 2;

    // ---- lift: 32 rows of h into resident LDS ----
    #pragma unroll
    for (int a = 0; a < 2; a++) {
        const int row = r + 16 * a, gr = row0 + row;
        float x0 = Acc<T>::ld(x, gr * 3 + 0);
        float x1 = Acc<T>::ld(x, gr * 3 + 1);
        float x2 = Acc<T>::ld(x, gr * 3 + 2);
        float o[4];
        #pragma unroll
        for (int b = 0; b < 4; b++) {
            int c = c4 + b;
            o[b] = Acc<T>::ld(lb, c) + x0 * Acc<T>::ld(lw, c)
                 + x1 * Acc<T>::ld(lw, DD + c) + x2 * Acc<T>::ld(lw, 2 * DD + c);
        }
        *(float4*)&sH[row][c4] = make_float4(o[0], o[1], o[2], o[3]);
    }
    __syncthreads();

    for (int layer = 0; layer < NLAYER; layer++) {
        const unsigned ep = (unsigned)(layer + 1);
        float* GgL = Gg + (size_t)(layer * NB + bb) * PSZ;
        const int wOff = layer * DD * DD, bOff = layer * DD;

        // ---- A: packed symmetric G-partial (upper triangle) into PS ----
        {
            if (i4 <= j4) {
                float m[4][4];
                #pragma unroll
                for (int a = 0; a < 4; a++)
                    #pragma unroll
                    for (int b = 0; b < 4; b++) m[a][b] = 0.f;
                #pragma unroll 8
                for (int n = 0; n < RPB; n++)
                    outer4x4(m, *(const float4*)&sH[n][r0], *(const float4*)&sH[n][c0]);
                float* dst = PS + (i4 * (33 - i4) / 2 + (j4 - i4)) * 16;
                #pragma unroll
                for (int a = 0; a < 4; a++)
                    #pragma unroll
                    for (int b = 0; b < 4; b++) dst[a * 4 + b] = m[a][b];
            }
            if (t < DD) {
                float ss = 0.f;
                #pragma unroll 8
                for (int n = 0; n < RPB; n++) ss += sH[n][t];
                PS[2176 + t] = ss;
                PS[2240 + t] = 0.f;     // pad (combine reduces it blindly)
            }
        }
        __syncthreads();
        // ---- B: wave-linear coherent copy PS -> own Gpart slot ----
        {
            float* slot = Gpart + (size_t)blk * PSZ;
            #pragma unroll
            for (int k2 = 0; k2 < 4; k2++) {
                const int idx = 2 * (t + k2 * NT);
                stc2(&slot[idx], PS[idx], PS[idx + 1]);
            }
            if (t < 128) {
                const int idx = 2 * (t + 4 * NT);
                stc2(&slot[idx], PS[idx], PS[idx + 1]);
            }
        }
        __syncthreads();                // vmcnt(0) per wave: partial fully visible
        if (t == 0) stw(&aflag[blk], ep);

        // ---- C: stage Wq/Wk + bias vectors while producers finish ----
        for (int i2 = t; i2 < DD * DD; i2 += NT) {
            B1[i2 >> 6][i2 & 63] = Acc<T>::ld(qw, wOff + i2);
            B4[i2 >> 6][i2 & 63] = Acc<T>::ld(kw, wOff + i2);
        }
        if (t < DD) {
            bkS[t] = Acc<T>::ld(kb, bOff + t);
            bqS[t] = Acc<T>::ld(qb, bOff + t);
            bvS[t] = Acc<T>::ld(vb, bOff + t);
        }

        // ---- D: combine own chunk across 128 slots of own batch ----
        {
            if (t < NCH) pollw(&aflag[bb * NCH + t], ep);
            __syncthreads();            // C staging complete + all partials seen
            const int chunk = blk & (NCH - 1);
            if (t < 144) {
                const int g = t / 9, p2 = t % 9;    // 16 slot-groups x 9 pairs
                const float* base = Gpart + (size_t)(bb * NCH + g * 8) * PSZ
                                  + chunk * CHW + 2 * p2;
                float ax = 0.f, ay = 0.f;
                #pragma unroll
                for (int s2 = 0; s2 < 8; s2++) {
                    float2 v = ldc2(base + (size_t)s2 * PSZ);
                    ax += v.x; ay += v.y;
                }
                RED[g * 20 + 2 * p2]     = ax;
                RED[g * 20 + 2 * p2 + 1] = ay;
            }
            __syncthreads();
            if (t < 9) {
                float s0 = 0.f, s1 = 0.f;
                #pragma unroll
                for (int g = 0; g < 16; g++) {
                    s0 += RED[g * 20 + 2 * t];
                    s1 += RED[g * 20 + 2 * t + 1];
                }
                stc2(&GgL[chunk * CHW + 2 * t], s0, s1);
            }
            __syncthreads();            // Gg stores drained
            if (t == 0) stw(&cflag[blk], ep);
        }

        // ---- E (cflag shadow): A = Wq@Wk^T, qk, kq, qbk; then Wv/Wb stage ----
        {
            float acc[4][4];
            #pragma unroll
            for (int a = 0; a < 4; a++)
                #pragma unroll
                for (int b = 0; b < 4; b++) acc[a][b] = 0.f;
            #pragma unroll 2
            for (int e = 0; e < DD; e += 4)
                mmNT4x4(acc,
                      *(const float4*)&B1[r0 + 0][e], *(const float4*)&B1[r0 + 1][e],
                      *(const float4*)&B1[r0 + 2][e], *(const float4*)&B1[r0 + 3][e],
                      *(const float4*)&B4[c0 + 0][e], *(const float4*)&B4[c0 + 1][e],
                      *(const float4*)&B4[c0 + 2][e], *(const float4*)&B4[c0 + 3][e]);
            #pragma unroll
            for (int a = 0; a < 4; a++)
                *(float4*)&B2[r0 + a][c0] = make_float4(acc[a][0], acc[a][1], acc[a][2], acc[a][3]);

            if (t < DD) {               // qk = Wq@bk
                float u = 0.f;
                for (int e = 0; e < DD; e++) u += B1[t][e] * bkS[e];
                qkS[t] = u;
            } else if (t < 2 * DD) {    // kq = Wk@bq
                const int rr = t - DD;
                float u = 0.f;
                for (int e = 0; e < DD; e++) u += B4[rr][e] * bqS[e];
                kqS[rr] = u;
            } else if (t == 2 * DD) {   // qbk = bq.bk
                float u = 0.f;
                for (int e = 0; e < DD; e++) u += bqS[e] * bkS[e];
                qbkS[0] = u;
            }
        }
        __syncthreads();                // B1/B4 free
        for (int i2 = t; i2 < DD * DD; i2 += NT) {
            B1[i2 >> 6][i2 & 63] = Acc<T>::ld(vw, wOff + i2);
            B4[i2 >> 6][i2 & 63] = Acc<T>::ld(blkw, wOff + i2);
        }

        // ---- F: wait all 128 chunks; stage G -> B3 (mirrored) ----
        {
            if (t < NCH) pollw(&cflag[bb * NCH + t], ep);
            __syncthreads();            // staging done + G visible
            // per-layer Gg + release-before-flag => normal CACHED loads safe
            if (i4 <= j4) {
                const float* src = GgL + (i4 * (33 - i4) / 2 + (j4 - i4)) * 16;
                #pragma unroll
                for (int a = 0; a < 4; a++)
                    *(float4*)&B3[r0 + a][c0] = *(const float4*)&src[a * 4];
            } else {
                const float* src = GgL + (j4 * (33 - j4) / 2 + (i4 - j4)) * 16;
                #pragma unroll
                for (int a = 0; a < 4; a++)
                    #pragma unroll
                    for (int b = 0; b < 4; b++)
                        B3[r0 + a][c0 + b] = src[b * 4 + a];
            }
            if (t < DD) sS[t] = GgL[2176 + t];
            __syncthreads();
        }

        // ---- G: B5 = T' = G@Wv + s bv^T ; red = su partials ----
        {
            float acc[4][4];
            #pragma unroll
            for (int a = 0; a < 4; a++)
                #pragma unroll
                for (int b = 0; b < 4; b++) acc[a][b] = sS[r0 + a] * bvS[c0 + b];
            #pragma unroll 2
            for (int e = 0; e < DD; e += 4)
                mm4x4(acc,
                      *(const float4*)&B3[r0 + 0][e], *(const float4*)&B3[r0 + 1][e],
                      *(const float4*)&B3[r0 + 2][e], *(const float4*)&B3[r0 + 3][e],
                      *(const float4*)&B1[e + 0][c0], *(const float4*)&B1[e + 1][c0],
                      *(const float4*)&B1[e + 2][c0], *(const float4*)&B1[e + 3][c0]);
            #pragma unroll
            for (int a = 0; a < 4; a++)
                *(float4*)&B5[r0 + a][c0] = make_float4(acc[a][0], acc[a][1], acc[a][2], acc[a][3]);
        }
        {   // su[c] = sum_d s[d]*Wv[d][c] partials (4 k-groups x 64 cols)
            const int c = t & 63, q = t >> 6;
            float u = 0.f;
            #pragma unroll
            for (int d2 = 0; d2 < 16; d2++) u += sS[q * 16 + d2] * B1[q * 16 + d2][c];
            red[q][c] = u;
        }
        __syncthreads();
        if (t < DD) suS[t] = red[0][t] + red[1][t] + red[2][t] + red[3][t] + (float)NN * bvS[t];
        __syncthreads();

        // ---- H: B3 = weff = Wb + C0*(A@T' + qk su^T) ; red = beff partials ----
        {
            float acc[4][4];
            #pragma unroll
            for (int a = 0; a < 4; a++)
                #pragma unroll
                for (int b = 0; b < 4; b++) acc[a][b] = qkS[r0 + a] * suS[c0 + b];
            #pragma unroll 2
            for (int e = 0; e < DD; e += 4)
                mm4x4(acc,
                      *(const float4*)&B2[r0 + 0][e], *(const float4*)&B2[r0 + 1][e],
                      *(const float4*)&B2[r0 + 2][e], *(const float4*)&B2[r0 + 3][e],
                      *(const float4*)&B5[e + 0][c0], *(const float4*)&B5[e + 1][c0],
                      *(const float4*)&B5[e + 2][c0], *(const float4*)&B5[e + 3][c0]);
            float wloc[4][4];
            #pragma unroll
            for (int a = 0; a < 4; a++)
                #pragma unroll
                for (int b = 0; b < 4; b++)
                    wloc[a][b] = B4[r0 + a][c0 + b] + C0F * acc[a][b];
            {   // beff partials BEFORE overwriting B3 (reads B5 only; safe)
                const int c = t & 63, q = t >> 6;
                float u = 0.f;
                #pragma unroll
                for (int e2 = 0; e2 < 16; e2++) u += kqS[q * 16 + e2] * B5[q * 16 + e2][c];
                red[q][c] = u;
            }
            __syncthreads();            // all G-reads of B3 done; red visible
            #pragma unroll
            for (int a = 0; a < 4; a++)
                *(float4*)&B3[r0 + a][c0] = make_float4(wloc[a][0], wloc[a][1], wloc[a][2], wloc[a][3]);
            if (t < DD) beS[t] = Acc<T>::ld(blkb, bOff + t)
                               + C0F * (red[0][t] + red[1][t] + red[2][t] + red[3][t]
                                        + qbkS[0] * suS[t]);
        }
        __syncthreads();

        // ---- apply: h' = gelu(h@weff + beff) on resident rows ----
        float o[2][4];
        #pragma unroll
        for (int a = 0; a < 2; a++) {
            const int row = r + 16 * a;
            float acc2[4];
            #pragma unroll
            for (int b = 0; b < 4; b++) acc2[b] = beS[c4 + b];
            for (int d = 0; d < DD; d++) {
                float hv = sH[row][d];
                float4 w4 = *(const float4*)&B3[d][c4];
                acc2[0] += hv * w4.x; acc2[1] += hv * w4.y;
                acc2[2] += hv * w4.z; acc2[3] += hv * w4.w;
            }
            #pragma unroll
            for (int b = 0; b < 4; b++) o[a][b] = gelu_exact(acc2[b]);
        }

        if (layer == NLAYER - 1) {
            float pbv = Acc<T>::ld(pb, 0);
            #pragma unroll
            for (int a = 0; a < 2; a++) {
                float p = 0.f;
                #pragma unroll
                for (int b = 0; b < 4; b++) p += o[a][b] * Acc<T>::ld(pw, c4 + b);
                p += __shfl_xor(p, 1);
                p += __shfl_xor(p, 2);
                p += __shfl_xor(p, 4);
                p += __shfl_xor(p, 8);
                if ((t & 15) == 0) Acc<T>::st(out, row0 + r + 16 * a, p + pbv);
            }
        } else {
            __syncthreads();    // weff/beS/sH reads done before sH overwrite
            #pragma unroll
            for (int a = 0; a < 2; a++)
                *(float4*)&sH[r + 16 * a][c4] =
                    make_float4(o[a][0], o[a][1], o[a][2], o[a][3]);
            __syncthreads();
        }
    }
}

__global__ __launch_bounds__(NT) void gno_kernel(
    const void* x, const void* lw, const void* lb,
    const void* blkw, const void* blkb,
    const void* qw, const void* qb, const void* kw, const void* kb,
    const void* vw, const void* vb, const void* pw, const void* pb,
    void* out, float* Gpart, float* Gg, unsigned* bar, int mode)
{
    __shared__ alignas(16) float smem[SM_TOT];   // 99072 B
    __shared__ int stot;

    const int blk = blockIdx.x, t = threadIdx.x;

    bool isbf;
    if (mode >= 0) {
        isbf = (mode == 1);
    } else {
        // fallback: device dtype scan (same result in every block)
        if (t == 0) stot = 0;
        __syncthreads();
        int cdt = 0;
        const unsigned int* xw = (const unsigned int*)x;
        for (int i = t; i < 8192; i += NT) {
            unsigned u = xw[i] & 0xFFFFu;
            int e = (u >> 7) & 0xFF;
            cdt += (u == 0u || (e >= 100 && e <= 142)) ? 1 : 0;
        }
        atomicAdd(&stot, cdt);
        __syncthreads();
        isbf = (stot > 4915);
    }

    unsigned* aflag = bar;          // [256] producer epochs
    unsigned* cflag = bar + 256;    // [256] combine epochs

    if (isbf)
        run_net<bf16>(x, lw, lb, blkw, blkb, qw, qb, kw, kb, vw, vb, pw, pb,
                      out, Gpart, Gg, aflag, cflag, smem, blk, t);
    else
        run_net<float>(x, lw, lb, blkw, blkb, qw, qb, kw, kb, vw, vb, pw, pb,
                       out, Gpart, Gg, aflag, cflag, smem, blk, t);
}

extern "C" void kernel_launch(void* const* d_in, const int* in_sizes, int n_in,
                              void* d_out, int out_size, void* d_ws, size_t ws_size,
                              hipStream_t stream)
{
    const void* x    = d_in[0];
    const void* lw   = d_in[1];
    const void* lb   = d_in[2];
    const void* blkw = d_in[3];
    const void* blkb = d_in[4];
    const void* qw   = d_in[5];
    const void* qb   = d_in[6];
    const void* kw   = d_in[7];
    const void* kb   = d_in[8];
    const void* vw   = d_in[9];
    const void* vb   = d_in[10];
    const void* pw   = d_in[11];
    const void* pb   = d_in[12];

    // x = [2,64,64,3]: fp32 -> 98304 B, bf16 -> 49152 B
    int mode = -1;
    if (in_sizes && n_in > 0) {
        if (in_sizes[0] == 49152) mode = 1;
        else if (in_sizes[0] == 98304) mode = 0;
    }

    unsigned* bar = (unsigned*)d_ws;                      // [512] flag words
    float* Gpart  = (float*)d_ws + 512;                   // [256][2304] 2.36 MB
    float* Gg     = Gpart + (size_t)NBLK * PSZ;           // [4][2][2304] per-layer

    (void)hipMemsetAsync(bar, 0, 512 * sizeof(unsigned), stream);
    gno_kernel<<<NBLK, NT, 0, stream>>>(x, lw, lb, blkw, blkb, qw, qb, kw, kb,
                                        vw, vb, pw, pb, d_out, Gpart, Gg, bar, mode);
}

// Round 13
// 154.245 us; speedup vs baseline: 1.0293x; 1.0293x over previous
//
#include <hip/hip_runtime.h>
#include <hip/hip_bf16.h>
#include <math.h>

// GNO collapsed: h = lift(x); per layer h = gelu(h@weff + beff),
//   weff = Wb + c0*(A@T' + qk su^T),  beff = bb + c0*(kq.T' + qbk su),
//   A = Wq@Wk^T, qk = Wq@bk, kq = Wk@bq, qbk = bq.bk     (G-INDEPENDENT)
//   T' = G@Wv + s bv^T,  su = Wv^T s + N bv,  G = h^T h, s = h^T 1.
// Round 25: champion fabric + T' computed INSIDE the combine.
//  - Combine reorganized: 64 row-blocks/batch reduce one full G ROW across
//    128 slots, immediately compute T'raw[row] = G[row]@Wv (Wv pre-staged
//    in C into B5), publish T'raw + s instead of G. Consumers' post-cflag
//    path loses the 2.5us T' matmul AND the G mirror-staging; they fold
//    the rank-1 s.bv^T while staging T'.
//  - Partials now store FULL G (4160 fl, no triangle packing) so rows are
//    contiguous; +80% partial traffic is affordable at 3% HBM.
//  - Non-combine blocks (rc>64) skip the aflag poll entirely.
//  - Everything else = champion verbatim (NT=256, 2 rounds/layer, stc2
//    stores, shadow E, host dtype detect). Decision rule: bench >= 157us
//    -> revert champion as final.

#define NLAYER 4
#define NB 2
#define NN 4096
#define DD 64
#define RPB 32              // rows per block (8192 rows / 256 blocks)
#define NT 256
#define NBLK 256
#define SHP 68              // padded LDS row stride (floats)
#define C0F (1.0f/32768.0f)
#define PSZ 4160            // partial floats: full G 4096 + s 64
#define NCH 128             // producers per batch

typedef __hip_bfloat16 bf16;
typedef unsigned long long u64t;

__device__ __forceinline__ float b2f(const bf16 v) { return __bfloat162float(v); }

template <typename T> struct Acc;
template <> struct Acc<float> {
    static __device__ __forceinline__ float ld(const void* p, int i) { return ((const float*)p)[i]; }
    static __device__ __forceinline__ void st(void* p, int i, float v) { ((float*)p)[i] = v; }
};
template <> struct Acc<bf16> {
    static __device__ __forceinline__ float ld(const void* p, int i) { return b2f(((const bf16*)p)[i]); }
    static __device__ __forceinline__ void st(void* p, int i, float v) { ((bf16*)p)[i] = __float2bfloat16(v); }
};

__device__ __forceinline__ float gelu_exact(float x) {
    return 0.5f * x * (1.0f + erff(x * 0.70710678118654752f));
}

// ---- device-coherent helpers (agent scope, relaxed) ----
__device__ __forceinline__ float2 ldc2(const float* p) {
    u64t v = __hip_atomic_load((const u64t*)p, __ATOMIC_RELAXED, __HIP_MEMORY_SCOPE_AGENT);
    float2 r;
    r.x = __uint_as_float((unsigned)v);
    r.y = __uint_as_float((unsigned)(v >> 32));
    return r;
}
__device__ __forceinline__ void stc2(float* p, float a, float b) {
    u64t v = ((u64t)__float_as_uint(b) << 32) | (u64t)__float_as_uint(a);
    __hip_atomic_store((u64t*)p, v, __ATOMIC_RELAXED, __HIP_MEMORY_SCOPE_AGENT);
}
__device__ __forceinline__ unsigned ldw(unsigned* p) {
    return __hip_atomic_load(p, __ATOMIC_RELAXED, __HIP_MEMORY_SCOPE_AGENT);
}
__device__ __forceinline__ void stw(unsigned* p, unsigned v) {
    __hip_atomic_store(p, v, __ATOMIC_RELAXED, __HIP_MEMORY_SCOPE_AGENT);
}
__device__ __forceinline__ void pollw(unsigned* p, unsigned ep) {
    int guard = 0;
    while (ldw(p) < ep && ++guard < (1 << 18)) __builtin_amdgcn_s_sleep(2);
}

// acc[a][b] += sum_k L[a].k * R[k].b   (NN product step)
__device__ __forceinline__ void mm4x4(float (&acc)[4][4],
    float4 L0, float4 L1, float4 L2, float4 L3,
    float4 R0, float4 R1, float4 R2, float4 R3)
{
    const float L[4][4] = {{L0.x,L0.y,L0.z,L0.w},{L1.x,L1.y,L1.z,L1.w},
                           {L2.x,L2.y,L2.z,L2.w},{L3.x,L3.y,L3.z,L3.w}};
    const float R[4][4] = {{R0.x,R0.y,R0.z,R0.w},{R1.x,R1.y,R1.z,R1.w},
                           {R2.x,R2.y,R2.z,R2.w},{R3.x,R3.y,R3.z,R3.w}};
    #pragma unroll
    for (int a = 0; a < 4; a++)
        #pragma unroll
        for (int k = 0; k < 4; k++)
            #pragma unroll
            for (int b = 0; b < 4; b++)
                acc[a][b] += L[a][k] * R[k][b];
}

// acc[a][b] += sum_k L[a].k * R[b].k   (NT product step: A = Wq @ Wk^T)
__device__ __forceinline__ void mmNT4x4(float (&acc)[4][4],
    float4 L0, float4 L1, float4 L2, float4 L3,
    float4 R0, float4 R1, float4 R2, float4 R3)
{
    const float L[4][4] = {{L0.x,L0.y,L0.z,L0.w},{L1.x,L1.y,L1.z,L1.w},
                           {L2.x,L2.y,L2.z,L2.w},{L3.x,L3.y,L3.z,L3.w}};
    const float R[4][4] = {{R0.x,R0.y,R0.z,R0.w},{R1.x,R1.y,R1.z,R1.w},
                           {R2.x,R2.y,R2.z,R2.w},{R3.x,R3.y,R3.z,R3.w}};
    #pragma unroll
    for (int a = 0; a < 4; a++)
        #pragma unroll
        for (int b = 0; b < 4; b++)
            #pragma unroll
            for (int k = 0; k < 4; k++)
                acc[a][b] += L[a][k] * R[b][k];
}

// acc[a][b] += A.a * B.b
__device__ __forceinline__ void outer4x4(float (&acc)[4][4], float4 A, float4 B)
{
    const float Aa[4] = {A.x, A.y, A.z, A.w};
    const float Ba[4] = {B.x, B.y, B.z, B.w};
    #pragma unroll
    for (int a = 0; a < 4; a++)
        #pragma unroll
        for (int b = 0; b < 4; b++)
            acc[a][b] += Aa[a] * Ba[b];
}

// LDS layout (floats):
//   sH  [32][68]  @ 0      resident h rows
//   B1  [64][68]  @ 2176   Wq
//   B2  [64][68]  @ 6528   A (shadow-computed, persists through weff)
//   B3  [64][68]  @ 10880  PS/combine scratch; then T'
//   B4  [64][68]  @ 15232  Wk -> Wb
//   B5  [64][68]  @ 19584  Wv -> weff
//   smalls @ 23936..24511 ; red [4][64] @ 24512
// total 24768 floats = 99072 B -> 1 block/CU, 256 blocks co-resident.

#define SM_SS   23936
#define SM_SU   24000
#define SM_BK   24064
#define SM_BQ   24128
#define SM_BV   24192
#define SM_BE   24256
#define SM_QK   24320
#define SM_KQ   24384
#define SM_QBK  24448
#define SM_RED  24512
#define SM_TOT  24768

template <typename T>
__device__ void run_net(
    const void* x, const void* lw, const void* lb,
    const void* blkw, const void* blkb,
    const void* qw, const void* qb, const void* kw, const void* kb,
    const void* vw, const void* vb, const void* pw, const void* pb,
    void* out, float* Gpart, float* Gg,
    unsigned* aflag, unsigned* cflag,
    float* smem, int blk, int t)
{
    float (*sH)[SHP] = (float(*)[SHP])(smem);
    float (*B1)[SHP] = (float(*)[SHP])(smem + 2176);
    float (*B2)[SHP] = (float(*)[SHP])(smem + 6528);
    float (*B3)[SHP] = (float(*)[SHP])(smem + 10880);
    float (*B4)[SHP] = (float(*)[SHP])(smem + 15232);
    float (*B5)[SHP] = (float(*)[SHP])(smem + 19584);
    float* PS  = smem + 10880;          // full-G partial scratch (aliases B3)
    float* RED = smem + 10880;          // combine scratch (aliases B3)
    float* sS  = smem + SM_SS;
    float* suS = smem + SM_SU;
    float* bkS = smem + SM_BK;
    float* bqS = smem + SM_BQ;
    float* bvS = smem + SM_BV;
    float* beS = smem + SM_BE;
    float* qkS = smem + SM_QK;
    float* kqS = smem + SM_KQ;
    float* qbkS = smem + SM_QBK;
    float (*red)[DD] = (float(*)[DD])(smem + SM_RED);

    const int row0 = blk * RPB;
    const int bb = blk >> 7;                      // batch of this block
    const int RC = blk & 127;                     // combine role: rows 0..63, s=64
    const int r = t >> 4, c4 = (t & 15) << 2;     // apply/lift mapping
    const int i4 = t >> 4, j4 = t & 15;           // 4x4 tile grid coords
    const int r0 = i4 << 2, c0 = j4 << 2;

    // ---- lift: 32 rows of h into resident LDS ----
    #pragma unroll
    for (int a = 0; a < 2; a++) {
        const int row = r + 16 * a, gr = row0 + row;
        float x0 = Acc<T>::ld(x, gr * 3 + 0);
        float x1 = Acc<T>::ld(x, gr * 3 + 1);
        float x2 = Acc<T>::ld(x, gr * 3 + 2);
        float o[4];
        #pragma unroll
        for (int b = 0; b < 4; b++) {
            int c = c4 + b;
            o[b] = Acc<T>::ld(lb, c) + x0 * Acc<T>::ld(lw, c)
                 + x1 * Acc<T>::ld(lw, DD + c) + x2 * Acc<T>::ld(lw, 2 * DD + c);
        }
        *(float4*)&sH[row][c4] = make_float4(o[0], o[1], o[2], o[3]);
    }
    __syncthreads();

    for (int layer = 0; layer < NLAYER; layer++) {
        const unsigned ep = (unsigned)(layer + 1);
        float* GgL = Gg + (size_t)(layer * NB + bb) * PSZ;   // T'raw[64][64] + s[64]
        const int wOff = layer * DD * DD, bOff = layer * DD;

        // ---- A: FULL G-partial (every thread computes its 4x4 tile) ----
        {
            float m[4][4];
            #pragma unroll
            for (int a = 0; a < 4; a++)
                #pragma unroll
                for (int b = 0; b < 4; b++) m[a][b] = 0.f;
            #pragma unroll 8
            for (int n = 0; n < RPB; n++)
                outer4x4(m, *(const float4*)&sH[n][r0], *(const float4*)&sH[n][c0]);
            #pragma unroll
            for (int a = 0; a < 4; a++)
                *(float4*)&PS[(r0 + a) * DD + c0] = make_float4(m[a][0], m[a][1], m[a][2], m[a][3]);
            if (t < DD) {
                float ss = 0.f;
                #pragma unroll 8
                for (int n = 0; n < RPB; n++) ss += sH[n][t];
                PS[4096 + t] = ss;
            }
        }
        __syncthreads();
        // ---- B: wave-linear coherent copy PS -> own Gpart slot (2080 pairs) ----
        {
            float* slot = Gpart + (size_t)blk * PSZ;
            #pragma unroll
            for (int k2 = 0; k2 < 8; k2++) {
                const int idx = 2 * (t + k2 * NT);
                stc2(&slot[idx], PS[idx], PS[idx + 1]);
            }
            if (t < 32) {
                const int idx = 2 * (t + 8 * NT);
                stc2(&slot[idx], PS[idx], PS[idx + 1]);
            }
        }
        __syncthreads();                // stc2 drained: partial fully visible
        if (t == 0) stw(&aflag[blk], ep);

        // ---- C: stage Wq->B1, Wk->B4, Wv->B5 + bias vectors ----
        for (int i2 = t; i2 < DD * DD; i2 += NT) {
            B1[i2 >> 6][i2 & 63] = Acc<T>::ld(qw, wOff + i2);
            B4[i2 >> 6][i2 & 63] = Acc<T>::ld(kw, wOff + i2);
            B5[i2 >> 6][i2 & 63] = Acc<T>::ld(vw, wOff + i2);
        }
        if (t < DD) {
            bkS[t] = Acc<T>::ld(kb, bOff + t);
            bqS[t] = Acc<T>::ld(qb, bOff + t);
            bvS[t] = Acc<T>::ld(vb, bOff + t);
        }

        // ---- D (combine roles only): reduce row RC across 128 slots;
        //      rows 0..63 also compute T'raw[RC] = G[RC]@Wv; RC==64 -> s ----
        if (RC <= 64) {
            if (t < NCH) pollw(&aflag[bb * NCH + t], ep);
            __syncthreads();            // C staging + all partials visible
            const int p2 = t & 31, g8 = t >> 5;      // 32 col-pairs x 8 slot-groups
            const int roff = (RC < 64) ? RC * DD : 4096;
            {
                const float* base = Gpart + (size_t)(bb * NCH + g8 * 16) * PSZ + roff + 2 * p2;
                float ax = 0.f, ay = 0.f;
                #pragma unroll
                for (int s2 = 0; s2 < 16; s2++) {
                    float2 v = ldc2(base + (size_t)s2 * PSZ);
                    ax += v.x; ay += v.y;
                }
                RED[g8 * 64 + 2 * p2]     = ax;
                RED[g8 * 64 + 2 * p2 + 1] = ay;
            }
            __syncthreads();
            if (RC < 64) {
                if (t < DD) {           // rowv = reduced G row
                    float u = 0.f;
                    #pragma unroll
                    for (int g = 0; g < 8; g++) u += RED[g * 64 + t];
                    RED[512 + t] = u;
                }
                __syncthreads();
                {   // T'raw[RC][c] partials over 4 e-groups
                    const int c = t & 63, q4 = t >> 6;
                    float u = 0.f;
                    #pragma unroll
                    for (int e2 = 0; e2 < 16; e2++)
                        u += RED[512 + q4 * 16 + e2] * B5[q4 * 16 + e2][c];
                    RED[576 + q4 * 64 + c] = u;
                }
                __syncthreads();
                if (t < 32) {
                    float v0 = 0.f, v1 = 0.f;
                    #pragma unroll
                    for (int q = 0; q < 4; q++) {
                        v0 += RED[576 + q * 64 + 2 * t];
                        v1 += RED[576 + q * 64 + 2 * t + 1];
                    }
                    stc2(&GgL[RC * DD + 2 * t], v0, v1);
                }
            } else {
                if (t < 32) {
                    float v0 = 0.f, v1 = 0.f;
                    #pragma unroll
                    for (int g = 0; g < 8; g++) {
                        v0 += RED[g * 64 + 2 * t];
                        v1 += RED[g * 64 + 2 * t + 1];
                    }
                    stc2(&GgL[4096 + 2 * t], v0, v1);
                }
            }
            __syncthreads();            // T'/s stores drained
            if (t == 0) stw(&cflag[blk], ep);
        }
        __syncthreads();                // C staging visible for non-combine blocks

        // ---- E: A = Wq@Wk^T (shadow), qk, kq, qbk ----
        {
            float acc[4][4];
            #pragma unroll
            for (int a = 0; a < 4; a++)
                #pragma unroll
                for (int b = 0; b < 4; b++) acc[a][b] = 0.f;
            #pragma unroll 2
            for (int e = 0; e < DD; e += 4)
                mmNT4x4(acc,
                      *(const float4*)&B1[r0 + 0][e], *(const float4*)&B1[r0 + 1][e],
                      *(const float4*)&B1[r0 + 2][e], *(const float4*)&B1[r0 + 3][e],
                      *(const float4*)&B4[c0 + 0][e], *(const float4*)&B4[c0 + 1][e],
                      *(const float4*)&B4[c0 + 2][e], *(const float4*)&B4[c0 + 3][e]);
            #pragma unroll
            for (int a = 0; a < 4; a++)
                *(float4*)&B2[r0 + a][c0] = make_float4(acc[a][0], acc[a][1], acc[a][2], acc[a][3]);

            if (t < DD) {               // qk = Wq@bk
                float u = 0.f;
                for (int e = 0; e < DD; e++) u += B1[t][e] * bkS[e];
                qkS[t] = u;
            } else if (t < 2 * DD) {    // kq = Wk@bq
                const int rr = t - DD;
                float u = 0.f;
                for (int e = 0; e < DD; e++) u += B4[rr][e] * bqS[e];
                kqS[rr] = u;
            } else if (t == 2 * DD) {   // qbk = bq.bk
                float u = 0.f;
                for (int e = 0; e < DD; e++) u += bqS[e] * bkS[e];
                qbkS[0] = u;
            }
        }
        __syncthreads();                // B4 (Wk) free; B1 free
        for (int i2 = t; i2 < DD * DD; i2 += NT)
            B4[i2 >> 6][i2 & 63] = Acc<T>::ld(blkw, wOff + i2);   // Wb

        // ---- F: wait 65 combine flags; stage T' = T'raw + s.bv^T -> B3 ----
        {
            if (t < 65) pollw(&cflag[bb * NCH + t], ep);
            __syncthreads();            // Wb staging + T'/s visible
            #pragma unroll
            for (int a = 0; a < 4; a++) {
                float4 v = *(const float4*)&GgL[(r0 + a) * DD + c0];
                const float sv = GgL[4096 + r0 + a];
                v.x += sv * bvS[c0 + 0];
                v.y += sv * bvS[c0 + 1];
                v.z += sv * bvS[c0 + 2];
                v.w += sv * bvS[c0 + 3];
                *(float4*)&B3[r0 + a][c0] = v;
            }
            if (t < DD) sS[t] = GgL[4096 + t];
            __syncthreads();
        }

        // ---- su: red = Wv^T s partials (B5 = Wv still live) ----
        {
            const int c = t & 63, q = t >> 6;
            float u = 0.f;
            #pragma unroll
            for (int d2 = 0; d2 < 16; d2++) u += sS[q * 16 + d2] * B5[q * 16 + d2][c];
            red[q][c] = u;
        }
        __syncthreads();
        if (t < DD) suS[t] = red[0][t] + red[1][t] + red[2][t] + red[3][t] + (float)NN * bvS[t];
        __syncthreads();

        // ---- H: weff = Wb + C0*(A@T' + qk su^T) -> B5 ; beff ----
        {
            float acc[4][4];
            #pragma unroll
            for (int a = 0; a < 4; a++)
                #pragma unroll
                for (int b = 0; b < 4; b++) acc[a][b] = qkS[r0 + a] * suS[c0 + b];
            #pragma unroll 2
            for (int e = 0; e < DD; e += 4)
                mm4x4(acc,
                      *(const float4*)&B2[r0 + 0][e], *(const float4*)&B2[r0 + 1][e],
                      *(const float4*)&B2[r0 + 2][e], *(const float4*)&B2[r0 + 3][e],
                      *(const float4*)&B3[e + 0][c0], *(const float4*)&B3[e + 1][c0],
                      *(const float4*)&B3[e + 2][c0], *(const float4*)&B3[e + 3][c0]);
            #pragma unroll
            for (int a = 0; a < 4; a++) {
                float4 w;
                w.x = B4[r0 + a][c0 + 0] + C0F * acc[a][0];
                w.y = B4[r0 + a][c0 + 1] + C0F * acc[a][1];
                w.z = B4[r0 + a][c0 + 2] + C0F * acc[a][2];
                w.w = B4[r0 + a][c0 + 3] + C0F * acc[a][3];
                *(float4*)&B5[r0 + a][c0] = w;      // B5 (Wv) dead after su
            }
            {   // beff partials: kq . T' (reads B3 only)
                const int c = t & 63, q = t >> 6;
                float u = 0.f;
                #pragma unroll
                for (int e2 = 0; e2 < 16; e2++) u += kqS[q * 16 + e2] * B3[q * 16 + e2][c];
                red[q][c] = u;
            }
            __syncthreads();            // red + weff visible
            if (t < DD) beS[t] = Acc<T>::ld(blkb, bOff + t)
                               + C0F * (red[0][t] + red[1][t] + red[2][t] + red[3][t]
                                        + qbkS[0] * suS[t]);
        }
        __syncthreads();

        // ---- apply: h' = gelu(h@weff + beff) on resident rows ----
        float o[2][4];
        #pragma unroll
        for (int a = 0; a < 2; a++) {
            const int row = r + 16 * a;
            float acc2[4];
            #pragma unroll
            for (int b = 0; b < 4; b++) acc2[b] = beS[c4 + b];
            for (int d = 0; d < DD; d++) {
                float hv = sH[row][d];
                float4 w4 = *(const float4*)&B5[d][c4];
                acc2[0] += hv * w4.x; acc2[1] += hv * w4.y;
                acc2[2] += hv * w4.z; acc2[3] += hv * w4.w;
            }
            #pragma unroll
            for (int b = 0; b < 4; b++) o[a][b] = gelu_exact(acc2[b]);
        }

        if (layer == NLAYER - 1) {
            float pbv = Acc<T>::ld(pb, 0);
            #pragma unroll
            for (int a = 0; a < 2; a++) {
                float p = 0.f;
                #pragma unroll
                for (int b = 0; b < 4; b++) p += o[a][b] * Acc<T>::ld(pw, c4 + b);
                p += __shfl_xor(p, 1);
                p += __shfl_xor(p, 2);
                p += __shfl_xor(p, 4);
                p += __shfl_xor(p, 8);
                if ((t & 15) == 0) Acc<T>::st(out, row0 + r + 16 * a, p + pbv);
            }
        } else {
            __syncthreads();    // weff/beS/sH reads done before sH overwrite
            #pragma unroll
            for (int a = 0; a < 2; a++)
                *(float4*)&sH[r + 16 * a][c4] =
                    make_float4(o[a][0], o[a][1], o[a][2], o[a][3]);
            __syncthreads();
        }
    }
}

__global__ __launch_bounds__(NT) void gno_kernel(
    const void* x, const void* lw, const void* lb,
    const void* blkw, const void* blkb,
    const void* qw, const void* qb, const void* kw, const void* kb,
    const void* vw, const void* vb, const void* pw, const void* pb,
    void* out, float* Gpart, float* Gg, unsigned* bar, int mode)
{
    __shared__ alignas(16) float smem[SM_TOT];   // 99072 B
    __shared__ int stot;

    const int blk = blockIdx.x, t = threadIdx.x;

    bool isbf;
    if (mode >= 0) {
        isbf = (mode == 1);
    } else {
        // fallback: device dtype scan (same result in every block)
        if (t == 0) stot = 0;
        __syncthreads();
        int cdt = 0;
        const unsigned int* xw = (const unsigned int*)x;
        for (int i = t; i < 8192; i += NT) {
            unsigned u = xw[i] & 0xFFFFu;
            int e = (u >> 7) & 0xFF;
            cdt += (u == 0u || (e >= 100 && e <= 142)) ? 1 : 0;
        }
        atomicAdd(&stot, cdt);
        __syncthreads();
        isbf = (stot > 4915);
    }

    unsigned* aflag = bar;          // [256] producer epochs
    unsigned* cflag = bar + 256;    // [256] combine epochs (65 used per batch)

    if (isbf)
        run_net<bf16>(x, lw, lb, blkw, blkb, qw, qb, kw, kb, vw, vb, pw, pb,
                      out, Gpart, Gg, aflag, cflag, smem, blk, t);
    else
        run_net<float>(x, lw, lb, blkw, blkb, qw, qb, kw, kb, vw, vb, pw, pb,
                       out, Gpart, Gg, aflag, cflag, smem, blk, t);
}

extern "C" void kernel_launch(void* const* d_in, const int* in_sizes, int n_in,
                              void* d_out, int out_size, void* d_ws, size_t ws_size,
                              hipStream_t stream)
{
    const void* x    = d_in[0];
    const void* lw   = d_in[1];
    const void* lb   = d_in[2];
    const void* blkw = d_in[3];
    const void* blkb = d_in[4];
    const void* qw   = d_in[5];
    const void* qb   = d_in[6];
    const void* kw   = d_in[7];
    const void* kb   = d_in[8];
    const void* vw   = d_in[9];
    const void* vb   = d_in[10];
    const void* pw   = d_in[11];
    const void* pb   = d_in[12];

    // x = [2,64,64,3]: fp32 -> 98304 B, bf16 -> 49152 B
    int mode = -1;
    if (in_sizes && n_in > 0) {
        if (in_sizes[0] == 49152) mode = 1;
        else if (in_sizes[0] == 98304) mode = 0;
    }

    unsigned* bar = (unsigned*)d_ws;                      // [512] flag words
    float* Gpart  = (float*)d_ws + 512;                   // [256][4160] 4.26 MB
    float* Gg     = Gpart + (size_t)NBLK * PSZ;           // [4][2][4160] T'raw+s

    (void)hipMemsetAsync(bar, 0, 512 * sizeof(unsigned), stream);
    gno_kernel<<<NBLK, NT, 0, stream>>>(x, lw, lb, blkw, blkb, qw, qb, kw, kb,
                                        vw, vb, pw, pb, d_out, Gpart, Gg, bar, mode);
}

// Round 14
// 152.270 us; speedup vs baseline: 1.0427x; 1.0130x over previous
//
#include <hip/hip_runtime.h>
#include <hip/hip_bf16.h>
#include <math.h>

// GNO collapsed: h = lift(x); per layer h = gelu(h@weff + beff),
//   weff = Wb + c0*(A@T' + qk su^T),  beff = bb + c0*(kq.T' + qbk su),
//   A = Wq@Wk^T, qk = Wq@bk, kq = Wk@bq, qbk = bq.bk     (G-INDEPENDENT)
//   T' = G@Wv + s bv^T,  su = Wv^T s + N bv,  G = h^T h, s = h^T 1.
// Round 26 = r25 (154.2us champion: T' computed inside the combine) + the
// s-block also computes AND publishes su = Wv^T s + N bv. Consumers skip
// the whole su phase (red partials + 2 barriers). Exact reassociation.
//  - Combine: 64 row-blocks/batch reduce one G ROW across 128 slots and
//    publish T'raw[row] = G[row]@Wv; block 64 reduces s, computes su,
//    publishes both.
//  - Consumers post-cflag: stage T' (+fold s.bv^T) -> H -> apply.
//  - Decision rule: bench >= 155us -> revert r25.

#define NLAYER 4
#define NB 2
#define NN 4096
#define DD 64
#define RPB 32              // rows per block (8192 rows / 256 blocks)
#define NT 256
#define NBLK 256
#define SHP 68              // padded LDS row stride (floats)
#define C0F (1.0f/32768.0f)
#define PSZ 4160            // partial floats: full G 4096 + s 64
#define GSZ 4224            // published floats: T'raw 4096 + s 64 + su 64
#define NCH 128             // producers per batch

typedef __hip_bfloat16 bf16;
typedef unsigned long long u64t;

__device__ __forceinline__ float b2f(const bf16 v) { return __bfloat162float(v); }

template <typename T> struct Acc;
template <> struct Acc<float> {
    static __device__ __forceinline__ float ld(const void* p, int i) { return ((const float*)p)[i]; }
    static __device__ __forceinline__ void st(void* p, int i, float v) { ((float*)p)[i] = v; }
};
template <> struct Acc<bf16> {
    static __device__ __forceinline__ float ld(const void* p, int i) { return b2f(((const bf16*)p)[i]); }
    static __device__ __forceinline__ void st(void* p, int i, float v) { ((bf16*)p)[i] = __float2bfloat16(v); }
};

__device__ __forceinline__ float gelu_exact(float x) {
    return 0.5f * x * (1.0f + erff(x * 0.70710678118654752f));
}

// ---- device-coherent helpers (agent scope, relaxed) ----
__device__ __forceinline__ float2 ldc2(const float* p) {
    u64t v = __hip_atomic_load((const u64t*)p, __ATOMIC_RELAXED, __HIP_MEMORY_SCOPE_AGENT);
    float2 r;
    r.x = __uint_as_float((unsigned)v);
    r.y = __uint_as_float((unsigned)(v >> 32));
    return r;
}
__device__ __forceinline__ void stc2(float* p, float a, float b) {
    u64t v = ((u64t)__float_as_uint(b) << 32) | (u64t)__float_as_uint(a);
    __hip_atomic_store((u64t*)p, v, __ATOMIC_RELAXED, __HIP_MEMORY_SCOPE_AGENT);
}
__device__ __forceinline__ unsigned ldw(unsigned* p) {
    return __hip_atomic_load(p, __ATOMIC_RELAXED, __HIP_MEMORY_SCOPE_AGENT);
}
__device__ __forceinline__ void stw(unsigned* p, unsigned v) {
    __hip_atomic_store(p, v, __ATOMIC_RELAXED, __HIP_MEMORY_SCOPE_AGENT);
}
__device__ __forceinline__ void pollw(unsigned* p, unsigned ep) {
    int guard = 0;
    while (ldw(p) < ep && ++guard < (1 << 18)) __builtin_amdgcn_s_sleep(2);
}

// acc[a][b] += sum_k L[a].k * R[k].b   (NN product step)
__device__ __forceinline__ void mm4x4(float (&acc)[4][4],
    float4 L0, float4 L1, float4 L2, float4 L3,
    float4 R0, float4 R1, float4 R2, float4 R3)
{
    const float L[4][4] = {{L0.x,L0.y,L0.z,L0.w},{L1.x,L1.y,L1.z,L1.w},
                           {L2.x,L2.y,L2.z,L2.w},{L3.x,L3.y,L3.z,L3.w}};
    const float R[4][4] = {{R0.x,R0.y,R0.z,R0.w},{R1.x,R1.y,R1.z,R1.w},
                           {R2.x,R2.y,R2.z,R2.w},{R3.x,R3.y,R3.z,R3.w}};
    #pragma unroll
    for (int a = 0; a < 4; a++)
        #pragma unroll
        for (int k = 0; k < 4; k++)
            #pragma unroll
            for (int b = 0; b < 4; b++)
                acc[a][b] += L[a][k] * R[k][b];
}

// acc[a][b] += sum_k L[a].k * R[b].k   (NT product step: A = Wq @ Wk^T)
__device__ __forceinline__ void mmNT4x4(float (&acc)[4][4],
    float4 L0, float4 L1, float4 L2, float4 L3,
    float4 R0, float4 R1, float4 R2, float4 R3)
{
    const float L[4][4] = {{L0.x,L0.y,L0.z,L0.w},{L1.x,L1.y,L1.z,L1.w},
                           {L2.x,L2.y,L2.z,L2.w},{L3.x,L3.y,L3.z,L3.w}};
    const float R[4][4] = {{R0.x,R0.y,R0.z,R0.w},{R1.x,R1.y,R1.z,R1.w},
                           {R2.x,R2.y,R2.z,R2.w},{R3.x,R3.y,R3.z,R3.w}};
    #pragma unroll
    for (int a = 0; a < 4; a++)
        #pragma unroll
        for (int b = 0; b < 4; b++)
            #pragma unroll
            for (int k = 0; k < 4; k++)
                acc[a][b] += L[a][k] * R[b][k];
}

// acc[a][b] += A.a * B.b
__device__ __forceinline__ void outer4x4(float (&acc)[4][4], float4 A, float4 B)
{
    const float Aa[4] = {A.x, A.y, A.z, A.w};
    const float Ba[4] = {B.x, B.y, B.z, B.w};
    #pragma unroll
    for (int a = 0; a < 4; a++)
        #pragma unroll
        for (int b = 0; b < 4; b++)
            acc[a][b] += Aa[a] * Ba[b];
}

// LDS layout (floats):
//   sH  [32][68]  @ 0      resident h rows
//   B1  [64][68]  @ 2176   Wq
//   B2  [64][68]  @ 6528   A (shadow-computed, persists through weff)
//   B3  [64][68]  @ 10880  PS/combine scratch; then T'
//   B4  [64][68]  @ 15232  Wk -> Wb
//   B5  [64][68]  @ 19584  Wv -> weff
//   smalls @ 23936..24511 ; red [4][64] @ 24512
// total 24768 floats = 99072 B -> 1 block/CU, 256 blocks co-resident.

#define SM_SS   23936
#define SM_SU   24000
#define SM_BK   24064
#define SM_BQ   24128
#define SM_BV   24192
#define SM_BE   24256
#define SM_QK   24320
#define SM_KQ   24384
#define SM_QBK  24448
#define SM_RED  24512
#define SM_TOT  24768

template <typename T>
__device__ void run_net(
    const void* x, const void* lw, const void* lb,
    const void* blkw, const void* blkb,
    const void* qw, const void* qb, const void* kw, const void* kb,
    const void* vw, const void* vb, const void* pw, const void* pb,
    void* out, float* Gpart, float* Gg,
    unsigned* aflag, unsigned* cflag,
    float* smem, int blk, int t)
{
    float (*sH)[SHP] = (float(*)[SHP])(smem);
    float (*B1)[SHP] = (float(*)[SHP])(smem + 2176);
    float (*B2)[SHP] = (float(*)[SHP])(smem + 6528);
    float (*B3)[SHP] = (float(*)[SHP])(smem + 10880);
    float (*B4)[SHP] = (float(*)[SHP])(smem + 15232);
    float (*B5)[SHP] = (float(*)[SHP])(smem + 19584);
    float* PS  = smem + 10880;          // full-G partial scratch (aliases B3)
    float* RED = smem + 10880;          // combine scratch (aliases B3)
    float* sS  = smem + SM_SS;
    float* suS = smem + SM_SU;
    float* bkS = smem + SM_BK;
    float* bqS = smem + SM_BQ;
    float* bvS = smem + SM_BV;
    float* beS = smem + SM_BE;
    float* qkS = smem + SM_QK;
    float* kqS = smem + SM_KQ;
    float* qbkS = smem + SM_QBK;
    float (*red)[DD] = (float(*)[DD])(smem + SM_RED);

    const int row0 = blk * RPB;
    const int bb = blk >> 7;                      // batch of this block
    const int RC = blk & 127;                     // combine role: rows 0..63, s/su=64
    const int r = t >> 4, c4 = (t & 15) << 2;     // apply/lift mapping
    const int i4 = t >> 4, j4 = t & 15;           // 4x4 tile grid coords
    const int r0 = i4 << 2, c0 = j4 << 2;

    // ---- lift: 32 rows of h into resident LDS ----
    #pragma unroll
    for (int a = 0; a < 2; a++) {
        const int row = r + 16 * a, gr = row0 + row;
        float x0 = Acc<T>::ld(x, gr * 3 + 0);
        float x1 = Acc<T>::ld(x, gr * 3 + 1);
        float x2 = Acc<T>::ld(x, gr * 3 + 2);
        float o[4];
        #pragma unroll
        for (int b = 0; b < 4; b++) {
            int c = c4 + b;
            o[b] = Acc<T>::ld(lb, c) + x0 * Acc<T>::ld(lw, c)
                 + x1 * Acc<T>::ld(lw, DD + c) + x2 * Acc<T>::ld(lw, 2 * DD + c);
        }
        *(float4*)&sH[row][c4] = make_float4(o[0], o[1], o[2], o[3]);
    }
    __syncthreads();

    for (int layer = 0; layer < NLAYER; layer++) {
        const unsigned ep = (unsigned)(layer + 1);
        float* GgL = Gg + (size_t)(layer * NB + bb) * GSZ;   // T'raw + s + su
        const int wOff = layer * DD * DD, bOff = layer * DD;

        // ---- A: FULL G-partial (every thread computes its 4x4 tile) ----
        {
            float m[4][4];
            #pragma unroll
            for (int a = 0; a < 4; a++)
                #pragma unroll
                for (int b = 0; b < 4; b++) m[a][b] = 0.f;
            #pragma unroll 8
            for (int n = 0; n < RPB; n++)
                outer4x4(m, *(const float4*)&sH[n][r0], *(const float4*)&sH[n][c0]);
            #pragma unroll
            for (int a = 0; a < 4; a++)
                *(float4*)&PS[(r0 + a) * DD + c0] = make_float4(m[a][0], m[a][1], m[a][2], m[a][3]);
            if (t < DD) {
                float ss = 0.f;
                #pragma unroll 8
                for (int n = 0; n < RPB; n++) ss += sH[n][t];
                PS[4096 + t] = ss;
            }
        }
        __syncthreads();
        // ---- B: wave-linear coherent copy PS -> own Gpart slot (2080 pairs) ----
        {
            float* slot = Gpart + (size_t)blk * PSZ;
            #pragma unroll
            for (int k2 = 0; k2 < 8; k2++) {
                const int idx = 2 * (t + k2 * NT);
                stc2(&slot[idx], PS[idx], PS[idx + 1]);
            }
            if (t < 32) {
                const int idx = 2 * (t + 8 * NT);
                stc2(&slot[idx], PS[idx], PS[idx + 1]);
            }
        }
        __syncthreads();                // stc2 drained: partial fully visible
        if (t == 0) stw(&aflag[blk], ep);

        // ---- C: stage Wq->B1, Wk->B4, Wv->B5 + bias vectors ----
        for (int i2 = t; i2 < DD * DD; i2 += NT) {
            B1[i2 >> 6][i2 & 63] = Acc<T>::ld(qw, wOff + i2);
            B4[i2 >> 6][i2 & 63] = Acc<T>::ld(kw, wOff + i2);
            B5[i2 >> 6][i2 & 63] = Acc<T>::ld(vw, wOff + i2);
        }
        if (t < DD) {
            bkS[t] = Acc<T>::ld(kb, bOff + t);
            bqS[t] = Acc<T>::ld(qb, bOff + t);
            bvS[t] = Acc<T>::ld(vb, bOff + t);
        }

        // ---- D (combine roles only): reduce row RC across 128 slots;
        //      rows 0..63 compute T'raw[RC] = G[RC]@Wv; RC==64 -> s AND su ----
        if (RC <= 64) {
            if (t < NCH) pollw(&aflag[bb * NCH + t], ep);
            __syncthreads();            // C staging + all partials visible
            const int p2 = t & 31, g8 = t >> 5;      // 32 col-pairs x 8 slot-groups
            const int roff = (RC < 64) ? RC * DD : 4096;
            {
                const float* base = Gpart + (size_t)(bb * NCH + g8 * 16) * PSZ + roff + 2 * p2;
                float ax = 0.f, ay = 0.f;
                #pragma unroll
                for (int s2 = 0; s2 < 16; s2++) {
                    float2 v = ldc2(base + (size_t)s2 * PSZ);
                    ax += v.x; ay += v.y;
                }
                RED[g8 * 64 + 2 * p2]     = ax;
                RED[g8 * 64 + 2 * p2 + 1] = ay;
            }
            __syncthreads();
            if (RC < 64) {
                if (t < DD) {           // rowv = reduced G row
                    float u = 0.f;
                    #pragma unroll
                    for (int g = 0; g < 8; g++) u += RED[g * 64 + t];
                    RED[512 + t] = u;
                }
                __syncthreads();
                {   // T'raw[RC][c] partials over 4 e-groups
                    const int c = t & 63, q4 = t >> 6;
                    float u = 0.f;
                    #pragma unroll
                    for (int e2 = 0; e2 < 16; e2++)
                        u += RED[512 + q4 * 16 + e2] * B5[q4 * 16 + e2][c];
                    RED[576 + q4 * 64 + c] = u;
                }
                __syncthreads();
                if (t < 32) {
                    float v0 = 0.f, v1 = 0.f;
                    #pragma unroll
                    for (int q = 0; q < 4; q++) {
                        v0 += RED[576 + q * 64 + 2 * t];
                        v1 += RED[576 + q * 64 + 2 * t + 1];
                    }
                    stc2(&GgL[RC * DD + 2 * t], v0, v1);
                }
            } else {
                if (t < DD) {           // s final
                    float u = 0.f;
                    #pragma unroll
                    for (int g = 0; g < 8; g++) u += RED[g * 64 + t];
                    RED[512 + t] = u;
                }
                __syncthreads();
                {   // su[c] partials: sum_d s[d]*Wv[d][c] over 4 d-groups
                    const int c = t & 63, q4 = t >> 6;
                    float u = 0.f;
                    #pragma unroll
                    for (int d2 = 0; d2 < 16; d2++)
                        u += RED[512 + q4 * 16 + d2] * B5[q4 * 16 + d2][c];
                    RED[576 + q4 * 64 + c] = u;
                }
                __syncthreads();
                if (t < 32) {
                    // publish s
                    stc2(&GgL[4096 + 2 * t], RED[512 + 2 * t], RED[512 + 2 * t + 1]);
                    // publish su = Wv^T s + N bv
                    float v0 = (float)NN * bvS[2 * t], v1 = (float)NN * bvS[2 * t + 1];
                    #pragma unroll
                    for (int q = 0; q < 4; q++) {
                        v0 += RED[576 + q * 64 + 2 * t];
                        v1 += RED[576 + q * 64 + 2 * t + 1];
                    }
                    stc2(&GgL[4160 + 2 * t], v0, v1);
                }
            }
            __syncthreads();            // T'/s/su stores drained
            if (t == 0) stw(&cflag[blk], ep);
        }
        __syncthreads();                // C staging visible for non-combine blocks

        // ---- E: A = Wq@Wk^T (shadow), qk, kq, qbk ----
        {
            float acc[4][4];
            #pragma unroll
            for (int a = 0; a < 4; a++)
                #pragma unroll
                for (int b = 0; b < 4; b++) acc[a][b] = 0.f;
            #pragma unroll 2
            for (int e = 0; e < DD; e += 4)
                mmNT4x4(acc,
                      *(const float4*)&B1[r0 + 0][e], *(const float4*)&B1[r0 + 1][e],
                      *(const float4*)&B1[r0 + 2][e], *(const float4*)&B1[r0 + 3][e],
                      *(const float4*)&B4[c0 + 0][e], *(const float4*)&B4[c0 + 1][e],
                      *(const float4*)&B4[c0 + 2][e], *(const float4*)&B4[c0 + 3][e]);
            #pragma unroll
            for (int a = 0; a < 4; a++)
                *(float4*)&B2[r0 + a][c0] = make_float4(acc[a][0], acc[a][1], acc[a][2], acc[a][3]);

            if (t < DD) {               // qk = Wq@bk
                float u = 0.f;
                for (int e = 0; e < DD; e++) u += B1[t][e] * bkS[e];
                qkS[t] = u;
            } else if (t < 2 * DD) {    // kq = Wk@bq
                const int rr = t - DD;
                float u = 0.f;
                for (int e = 0; e < DD; e++) u += B4[rr][e] * bqS[e];
                kqS[rr] = u;
            } else if (t == 2 * DD) {   // qbk = bq.bk
                float u = 0.f;
                for (int e = 0; e < DD; e++) u += bqS[e] * bkS[e];
                qbkS[0] = u;
            }
        }
        __syncthreads();                // B4 (Wk) free; B1 free
        for (int i2 = t; i2 < DD * DD; i2 += NT)
            B4[i2 >> 6][i2 & 63] = Acc<T>::ld(blkw, wOff + i2);   // Wb

        // ---- F: wait 65 combine flags; stage T' = T'raw + s.bv^T -> B3;
        //      load s and su directly (su phase deleted) ----
        {
            if (t < 65) pollw(&cflag[bb * NCH + t], ep);
            __syncthreads();            // Wb staging + T'/s/su visible
            #pragma unroll
            for (int a = 0; a < 4; a++) {
                float4 v = *(const float4*)&GgL[(r0 + a) * DD + c0];
                const float sv = GgL[4096 + r0 + a];
                v.x += sv * bvS[c0 + 0];
                v.y += sv * bvS[c0 + 1];
                v.z += sv * bvS[c0 + 2];
                v.w += sv * bvS[c0 + 3];
                *(float4*)&B3[r0 + a][c0] = v;
            }
            if (t < DD) suS[t] = GgL[4160 + t];
            __syncthreads();
        }

        // ---- H: weff = Wb + C0*(A@T' + qk su^T) -> B5 ; beff ----
        {
            float acc[4][4];
            #pragma unroll
            for (int a = 0; a < 4; a++)
                #pragma unroll
                for (int b = 0; b < 4; b++) acc[a][b] = qkS[r0 + a] * suS[c0 + b];
            #pragma unroll 2
            for (int e = 0; e < DD; e += 4)
                mm4x4(acc,
                      *(const float4*)&B2[r0 + 0][e], *(const float4*)&B2[r0 + 1][e],
                      *(const float4*)&B2[r0 + 2][e], *(const float4*)&B2[r0 + 3][e],
                      *(const float4*)&B3[e + 0][c0], *(const float4*)&B3[e + 1][c0],
                      *(const float4*)&B3[e + 2][c0], *(const float4*)&B3[e + 3][c0]);
            #pragma unroll
            for (int a = 0; a < 4; a++) {
                float4 w;
                w.x = B4[r0 + a][c0 + 0] + C0F * acc[a][0];
                w.y = B4[r0 + a][c0 + 1] + C0F * acc[a][1];
                w.z = B4[r0 + a][c0 + 2] + C0F * acc[a][2];
                w.w = B4[r0 + a][c0 + 3] + C0F * acc[a][3];
                *(float4*)&B5[r0 + a][c0] = w;      // B5 (Wv) dead after combine
            }
            {   // beff partials: kq . T' (reads B3 only)
                const int c = t & 63, q = t >> 6;
                float u = 0.f;
                #pragma unroll
                for (int e2 = 0; e2 < 16; e2++) u += kqS[q * 16 + e2] * B3[q * 16 + e2][c];
                red[q][c] = u;
            }
            __syncthreads();            // red + weff visible
            if (t < DD) beS[t] = Acc<T>::ld(blkb, bOff + t)
                               + C0F * (red[0][t] + red[1][t] + red[2][t] + red[3][t]
                                        + qbkS[0] * suS[t]);
        }
        __syncthreads();

        // ---- apply: h' = gelu(h@weff + beff) on resident rows ----
        float o[2][4];
        #pragma unroll
        for (int a = 0; a < 2; a++) {
            const int row = r + 16 * a;
            float acc2[4];
            #pragma unroll
            for (int b = 0; b < 4; b++) acc2[b] = beS[c4 + b];
            for (int d = 0; d < DD; d++) {
                float hv = sH[row][d];
                float4 w4 = *(const float4*)&B5[d][c4];
                acc2[0] += hv * w4.x; acc2[1] += hv * w4.y;
                acc2[2] += hv * w4.z; acc2[3] += hv * w4.w;
            }
            #pragma unroll
            for (int b = 0; b < 4; b++) o[a][b] = gelu_exact(acc2[b]);
        }

        if (layer == NLAYER - 1) {
            float pbv = Acc<T>::ld(pb, 0);
            #pragma unroll
            for (int a = 0; a < 2; a++) {
                float p = 0.f;
                #pragma unroll
                for (int b = 0; b < 4; b++) p += o[a][b] * Acc<T>::ld(pw, c4 + b);
                p += __shfl_xor(p, 1);
                p += __shfl_xor(p, 2);
                p += __shfl_xor(p, 4);
                p += __shfl_xor(p, 8);
                if ((t & 15) == 0) Acc<T>::st(out, row0 + r + 16 * a, p + pbv);
            }
        } else {
            __syncthreads();    // weff/beS/sH reads done before sH overwrite
            #pragma unroll
            for (int a = 0; a < 2; a++)
                *(float4*)&sH[r + 16 * a][c4] =
                    make_float4(o[a][0], o[a][1], o[a][2], o[a][3]);
            __syncthreads();
        }
    }
}

__global__ __launch_bounds__(NT) void gno_kernel(
    const void* x, const void* lw, const void* lb,
    const void* blkw, const void* blkb,
    const void* qw, const void* qb, const void* kw, const void* kb,
    const void* vw, const void* vb, const void* pw, const void* pb,
    void* out, float* Gpart, float* Gg, unsigned* bar, int mode)
{
    __shared__ alignas(16) float smem[SM_TOT];   // 99072 B
    __shared__ int stot;

    const int blk = blockIdx.x, t = threadIdx.x;

    bool isbf;
    if (mode >= 0) {
        isbf = (mode == 1);
    } else {
        // fallback: device dtype scan (same result in every block)
        if (t == 0) stot = 0;
        __syncthreads();
        int cdt = 0;
        const unsigned int* xw = (const unsigned int*)x;
        for (int i = t; i < 8192; i += NT) {
            unsigned u = xw[i] & 0xFFFFu;
            int e = (u >> 7) & 0xFF;
            cdt += (u == 0u || (e >= 100 && e <= 142)) ? 1 : 0;
        }
        atomicAdd(&stot, cdt);
        __syncthreads();
        isbf = (stot > 4915);
    }

    unsigned* aflag = bar;          // [256] producer epochs
    unsigned* cflag = bar + 256;    // [256] combine epochs (65 used per batch)

    if (isbf)
        run_net<bf16>(x, lw, lb, blkw, blkb, qw, qb, kw, kb, vw, vb, pw, pb,
                      out, Gpart, Gg, aflag, cflag, smem, blk, t);
    else
        run_net<float>(x, lw, lb, blkw, blkb, qw, qb, kw, kb, vw, vb, pw, pb,
                       out, Gpart, Gg, aflag, cflag, smem, blk, t);
}

extern "C" void kernel_launch(void* const* d_in, const int* in_sizes, int n_in,
                              void* d_out, int out_size, void* d_ws, size_t ws_size,
                              hipStream_t stream)
{
    const void* x    = d_in[0];
    const void* lw   = d_in[1];
    const void* lb   = d_in[2];
    const void* blkw = d_in[3];
    const void* blkb = d_in[4];
    const void* qw   = d_in[5];
    const void* qb   = d_in[6];
    const void* kw   = d_in[7];
    const void* kb   = d_in[8];
    const void* vw   = d_in[9];
    const void* vb   = d_in[10];
    const void* pw   = d_in[11];
    const void* pb   = d_in[12];

    // x = [2,64,64,3]: fp32 -> 98304 B, bf16 -> 49152 B
    int mode = -1;
    if (in_sizes && n_in > 0) {
        if (in_sizes[0] == 49152) mode = 1;
        else if (in_sizes[0] == 98304) mode = 0;
    }

    unsigned* bar = (unsigned*)d_ws;                      // [512] flag words
    float* Gpart  = (float*)d_ws + 512;                   // [256][4160] 4.26 MB
    float* Gg     = Gpart + (size_t)NBLK * PSZ;           // [4][2][4224] T'raw+s+su

    (void)hipMemsetAsync(bar, 0, 512 * sizeof(unsigned), stream);
    gno_kernel<<<NBLK, NT, 0, stream>>>(x, lw, lb, blkw, blkb, qw, qb, kw, kb,
                                        vw, vb, pw, pb, d_out, Gpart, Gg, bar, mode);
}

// Round 15
// 150.587 us; speedup vs baseline: 1.0543x; 1.0112x over previous
//
#include <hip/hip_runtime.h>
#include <hip/hip_bf16.h>
#include <math.h>

// GNO collapsed: h = lift(x); per layer h = gelu(h@weff + beff),
//   weff = Wb + c0*(A@T' + qk su^T),  beff = bb + c0*(kq.T' + qbk su),
//   A = Wq@Wk^T, qk = Wq@bk, kq = Wk@bq, qbk = bq.bk     (G-INDEPENDENT)
//   T' = G@Wv + s bv^T,  su = Wv^T s + N bv,  G = h^T h, s = h^T 1.
// Round 27 = r26 (152.3us: combine computes T'+su) + producer path
// shortened: G-partials stored DIRECTLY to the slot (no PS/LDS staging,
// one barrier deleted). Write-combining preserved via PERMUTED row layout:
// each stc2 instruction covers a contiguous 128B line across its 16-lane
// group (perm: col c -> ((c&3)>>1)*32 + (c>>2)*2 + (c&1)). The combine's
// blind pair-reduce is layout-agnostic; only its G-row x Wv multiply uses
// the inverse perm (compile-time). s stored natural (contiguous 4B).
// T'raw/s/su published natural -> consumer F/H/apply untouched.
// Decision rule: bench >= 153us -> revert r26.

#define NLAYER 4
#define NB 2
#define NN 4096
#define DD 64
#define RPB 32              // rows per block (8192 rows / 256 blocks)
#define NT 256
#define NBLK 256
#define SHP 68              // padded LDS row stride (floats)
#define C0F (1.0f/32768.0f)
#define PSZ 4160            // partial floats: full G 4096 (permuted rows) + s 64
#define GSZ 4224            // published floats: T'raw 4096 + s 64 + su 64
#define NCH 128             // producers per batch

typedef __hip_bfloat16 bf16;
typedef unsigned long long u64t;

__device__ __forceinline__ float b2f(const bf16 v) { return __bfloat162float(v); }

template <typename T> struct Acc;
template <> struct Acc<float> {
    static __device__ __forceinline__ float ld(const void* p, int i) { return ((const float*)p)[i]; }
    static __device__ __forceinline__ void st(void* p, int i, float v) { ((float*)p)[i] = v; }
};
template <> struct Acc<bf16> {
    static __device__ __forceinline__ float ld(const void* p, int i) { return b2f(((const bf16*)p)[i]); }
    static __device__ __forceinline__ void st(void* p, int i, float v) { ((bf16*)p)[i] = __float2bfloat16(v); }
};

__device__ __forceinline__ float gelu_exact(float x) {
    return 0.5f * x * (1.0f + erff(x * 0.70710678118654752f));
}

// ---- device-coherent helpers (agent scope, relaxed) ----
__device__ __forceinline__ float2 ldc2(const float* p) {
    u64t v = __hip_atomic_load((const u64t*)p, __ATOMIC_RELAXED, __HIP_MEMORY_SCOPE_AGENT);
    float2 r;
    r.x = __uint_as_float((unsigned)v);
    r.y = __uint_as_float((unsigned)(v >> 32));
    return r;
}
__device__ __forceinline__ void stc(float* p, float v) {
    __hip_atomic_store((unsigned*)p, __float_as_uint(v), __ATOMIC_RELAXED, __HIP_MEMORY_SCOPE_AGENT);
}
__device__ __forceinline__ void stc2(float* p, float a, float b) {
    u64t v = ((u64t)__float_as_uint(b) << 32) | (u64t)__float_as_uint(a);
    __hip_atomic_store((u64t*)p, v, __ATOMIC_RELAXED, __HIP_MEMORY_SCOPE_AGENT);
}
__device__ __forceinline__ unsigned ldw(unsigned* p) {
    return __hip_atomic_load(p, __ATOMIC_RELAXED, __HIP_MEMORY_SCOPE_AGENT);
}
__device__ __forceinline__ void stw(unsigned* p, unsigned v) {
    __hip_atomic_store(p, v, __ATOMIC_RELAXED, __HIP_MEMORY_SCOPE_AGENT);
}
__device__ __forceinline__ void pollw(unsigned* p, unsigned ep) {
    int guard = 0;
    while (ldw(p) < ep && ++guard < (1 << 18)) __builtin_amdgcn_s_sleep(2);
}

// acc[a][b] += sum_k L[a].k * R[k].b   (NN product step)
__device__ __forceinline__ void mm4x4(float (&acc)[4][4],
    float4 L0, float4 L1, float4 L2, float4 L3,
    float4 R0, float4 R1, float4 R2, float4 R3)
{
    const float L[4][4] = {{L0.x,L0.y,L0.z,L0.w},{L1.x,L1.y,L1.z,L1.w},
                           {L2.x,L2.y,L2.z,L2.w},{L3.x,L3.y,L3.z,L3.w}};
    const float R[4][4] = {{R0.x,R0.y,R0.z,R0.w},{R1.x,R1.y,R1.z,R1.w},
                           {R2.x,R2.y,R2.z,R2.w},{R3.x,R3.y,R3.z,R3.w}};
    #pragma unroll
    for (int a = 0; a < 4; a++)
        #pragma unroll
        for (int k = 0; k < 4; k++)
            #pragma unroll
            for (int b = 0; b < 4; b++)
                acc[a][b] += L[a][k] * R[k][b];
}

// acc[a][b] += sum_k L[a].k * R[b].k   (NT product step: A = Wq @ Wk^T)
__device__ __forceinline__ void mmNT4x4(float (&acc)[4][4],
    float4 L0, float4 L1, float4 L2, float4 L3,
    float4 R0, float4 R1, float4 R2, float4 R3)
{
    const float L[4][4] = {{L0.x,L0.y,L0.z,L0.w},{L1.x,L1.y,L1.z,L1.w},
                           {L2.x,L2.y,L2.z,L2.w},{L3.x,L3.y,L3.z,L3.w}};
    const float R[4][4] = {{R0.x,R0.y,R0.z,R0.w},{R1.x,R1.y,R1.z,R1.w},
                           {R2.x,R2.y,R2.z,R2.w},{R3.x,R3.y,R3.z,R3.w}};
    #pragma unroll
    for (int a = 0; a < 4; a++)
        #pragma unroll
        for (int b = 0; b < 4; b++)
            #pragma unroll
            for (int k = 0; k < 4; k++)
                acc[a][b] += L[a][k] * R[b][k];
}

// acc[a][b] += A.a * B.b
__device__ __forceinline__ void outer4x4(float (&acc)[4][4], float4 A, float4 B)
{
    const float Aa[4] = {A.x, A.y, A.z, A.w};
    const float Ba[4] = {B.x, B.y, B.z, B.w};
    #pragma unroll
    for (int a = 0; a < 4; a++)
        #pragma unroll
        for (int b = 0; b < 4; b++)
            acc[a][b] += Aa[a] * Ba[b];
}

// LDS layout (floats):
//   sH  [32][68]  @ 0      resident h rows
//   B1  [64][68]  @ 2176   Wq
//   B2  [64][68]  @ 6528   A (shadow-computed, persists through weff)
//   B3  [64][68]  @ 10880  combine scratch RED; then T'
//   B4  [64][68]  @ 15232  Wk -> Wb
//   B5  [64][68]  @ 19584  Wv -> weff
//   smalls @ 23936..24511 ; red [4][64] @ 24512
// total 24768 floats = 99072 B -> 1 block/CU, 256 blocks co-resident.

#define SM_SS   23936
#define SM_SU   24000
#define SM_BK   24064
#define SM_BQ   24128
#define SM_BV   24192
#define SM_BE   24256
#define SM_QK   24320
#define SM_KQ   24384
#define SM_QBK  24448
#define SM_RED  24512
#define SM_TOT  24768

template <typename T>
__device__ void run_net(
    const void* x, const void* lw, const void* lb,
    const void* blkw, const void* blkb,
    const void* qw, const void* qb, const void* kw, const void* kb,
    const void* vw, const void* vb, const void* pw, const void* pb,
    void* out, float* Gpart, float* Gg,
    unsigned* aflag, unsigned* cflag,
    float* smem, int blk, int t)
{
    float (*sH)[SHP] = (float(*)[SHP])(smem);
    float (*B1)[SHP] = (float(*)[SHP])(smem + 2176);
    float (*B2)[SHP] = (float(*)[SHP])(smem + 6528);
    float (*B3)[SHP] = (float(*)[SHP])(smem + 10880);
    float (*B4)[SHP] = (float(*)[SHP])(smem + 15232);
    float (*B5)[SHP] = (float(*)[SHP])(smem + 19584);
    float* RED = smem + 10880;          // combine scratch (aliases B3)
    float* suS = smem + SM_SU;
    float* bkS = smem + SM_BK;
    float* bqS = smem + SM_BQ;
    float* bvS = smem + SM_BV;
    float* beS = smem + SM_BE;
    float* qkS = smem + SM_QK;
    float* kqS = smem + SM_KQ;
    float* qbkS = smem + SM_QBK;
    float (*red)[DD] = (float(*)[DD])(smem + SM_RED);

    const int row0 = blk * RPB;
    const int bb = blk >> 7;                      // batch of this block
    const int RC = blk & 127;                     // combine role: rows 0..63, s/su=64
    const int r = t >> 4, c4 = (t & 15) << 2;     // apply/lift mapping
    const int i4 = t >> 4, j4 = t & 15;           // 4x4 tile grid coords
    const int r0 = i4 << 2, c0 = j4 << 2;

    // ---- lift: 32 rows of h into resident LDS ----
    #pragma unroll
    for (int a = 0; a < 2; a++) {
        const int row = r + 16 * a, gr = row0 + row;
        float x0 = Acc<T>::ld(x, gr * 3 + 0);
        float x1 = Acc<T>::ld(x, gr * 3 + 1);
        float x2 = Acc<T>::ld(x, gr * 3 + 2);
        float o[4];
        #pragma unroll
        for (int b = 0; b < 4; b++) {
            int c = c4 + b;
            o[b] = Acc<T>::ld(lb, c) + x0 * Acc<T>::ld(lw, c)
                 + x1 * Acc<T>::ld(lw, DD + c) + x2 * Acc<T>::ld(lw, 2 * DD + c);
        }
        *(float4*)&sH[row][c4] = make_float4(o[0], o[1], o[2], o[3]);
    }
    __syncthreads();

    for (int layer = 0; layer < NLAYER; layer++) {
        const unsigned ep = (unsigned)(layer + 1);
        float* GgL = Gg + (size_t)(layer * NB + bb) * GSZ;   // T'raw + s + su
        const int wOff = layer * DD * DD, bOff = layer * DD;

        // ---- A: G-partial computed and stored DIRECTLY (permuted rows) ----
        // Row layout in slot: [pair(4g,4g+1) for g=0..15][pair(4g+2,4g+3)...]
        // -> each stc2 instr covers 128B contiguous per 16-lane group.
        {
            float* slot = Gpart + (size_t)blk * PSZ;
            float m[4][4];
            #pragma unroll
            for (int a = 0; a < 4; a++)
                #pragma unroll
                for (int b = 0; b < 4; b++) m[a][b] = 0.f;
            #pragma unroll 8
            for (int n = 0; n < RPB; n++)
                outer4x4(m, *(const float4*)&sH[n][r0], *(const float4*)&sH[n][c0]);
            #pragma unroll
            for (int a = 0; a < 4; a++) {
                float* rowp = slot + (r0 + a) * DD;
                stc2(rowp + 2 * j4,      m[a][0], m[a][1]);
                stc2(rowp + 32 + 2 * j4, m[a][2], m[a][3]);
            }
            if (t < DD) {
                float ss = 0.f;
                #pragma unroll 8
                for (int n = 0; n < RPB; n++) ss += sH[n][t];
                stc(&slot[4096 + t], ss);   // natural order, contiguous 4B
            }
        }
        __syncthreads();                // vmcnt(0) per wave: partial fully visible
        if (t == 0) stw(&aflag[blk], ep);

        // ---- C: stage Wq->B1, Wk->B4, Wv->B5 + bias vectors ----
        for (int i2 = t; i2 < DD * DD; i2 += NT) {
            B1[i2 >> 6][i2 & 63] = Acc<T>::ld(qw, wOff + i2);
            B4[i2 >> 6][i2 & 63] = Acc<T>::ld(kw, wOff + i2);
            B5[i2 >> 6][i2 & 63] = Acc<T>::ld(vw, wOff + i2);
        }
        if (t < DD) {
            bkS[t] = Acc<T>::ld(kb, bOff + t);
            bqS[t] = Acc<T>::ld(qb, bOff + t);
            bvS[t] = Acc<T>::ld(vb, bOff + t);
        }

        // ---- D (combine roles only): reduce row RC across 128 slots;
        //      rows 0..63 compute T'raw[RC] = G[RC]@Wv; RC==64 -> s AND su ----
        if (RC <= 64) {
            if (t < NCH) pollw(&aflag[bb * NCH + t], ep);
            __syncthreads();            // C staging + all partials visible
            const int p2 = t & 31, g8 = t >> 5;      // 32 pair-slots x 8 slot-groups
            const int roff = (RC < 64) ? RC * DD : 4096;
            {
                const float* base = Gpart + (size_t)(bb * NCH + g8 * 16) * PSZ + roff + 2 * p2;
                float ax = 0.f, ay = 0.f;
                #pragma unroll
                for (int s2 = 0; s2 < 16; s2++) {
                    float2 v = ldc2(base + (size_t)s2 * PSZ);
                    ax += v.x; ay += v.y;
                }
                RED[g8 * 64 + 2 * p2]     = ax;
                RED[g8 * 64 + 2 * p2 + 1] = ay;
            }
            __syncthreads();
            if (RC < 64) {
                if (t < DD) {           // RED[512+p] = reduced G row, PERMUTED idx p
                    float u = 0.f;
                    #pragma unroll
                    for (int g = 0; g < 8; g++) u += RED[g * 64 + t];
                    RED[512 + t] = u;
                }
                __syncthreads();
                {   // T'raw[RC][c] partials; e = q4*16+e2 natural -> perm index
                    const int c = t & 63, q4 = t >> 6;
                    float u = 0.f;
                    #pragma unroll
                    for (int e2 = 0; e2 < 16; e2++) {
                        const int pidx = ((e2 & 2) << 4) + q4 * 8 + ((e2 >> 2) << 1) + (e2 & 1);
                        u += RED[512 + pidx] * B5[q4 * 16 + e2][c];
                    }
                    RED[576 + q4 * 64 + c] = u;
                }
                __syncthreads();
                if (t < 32) {
                    float v0 = 0.f, v1 = 0.f;
                    #pragma unroll
                    for (int q = 0; q < 4; q++) {
                        v0 += RED[576 + q * 64 + 2 * t];
                        v1 += RED[576 + q * 64 + 2 * t + 1];
                    }
                    stc2(&GgL[RC * DD + 2 * t], v0, v1);
                }
            } else {
                if (t < DD) {           // s final (stored natural -> natural here)
                    float u = 0.f;
                    #pragma unroll
                    for (int g = 0; g < 8; g++) u += RED[g * 64 + t];
                    RED[512 + t] = u;
                }
                __syncthreads();
                {   // su[c] partials: sum_d s[d]*Wv[d][c] over 4 d-groups
                    const int c = t & 63, q4 = t >> 6;
                    float u = 0.f;
                    #pragma unroll
                    for (int d2 = 0; d2 < 16; d2++)
                        u += RED[512 + q4 * 16 + d2] * B5[q4 * 16 + d2][c];
                    RED[576 + q4 * 64 + c] = u;
                }
                __syncthreads();
                if (t < 32) {
                    // publish s
                    stc2(&GgL[4096 + 2 * t], RED[512 + 2 * t], RED[512 + 2 * t + 1]);
                    // publish su = Wv^T s + N bv
                    float v0 = (float)NN * bvS[2 * t], v1 = (float)NN * bvS[2 * t + 1];
                    #pragma unroll
                    for (int q = 0; q < 4; q++) {
                        v0 += RED[576 + q * 64 + 2 * t];
                        v1 += RED[576 + q * 64 + 2 * t + 1];
                    }
                    stc2(&GgL[4160 + 2 * t], v0, v1);
                }
            }
            __syncthreads();            // T'/s/su stores drained
            if (t == 0) stw(&cflag[blk], ep);
        }
        __syncthreads();                // C staging visible for non-combine blocks

        // ---- E: A = Wq@Wk^T (shadow), qk, kq, qbk ----
        {
            float acc[4][4];
            #pragma unroll
            for (int a = 0; a < 4; a++)
                #pragma unroll
                for (int b = 0; b < 4; b++) acc[a][b] = 0.f;
            #pragma unroll 2
            for (int e = 0; e < DD; e += 4)
                mmNT4x4(acc,
                      *(const float4*)&B1[r0 + 0][e], *(const float4*)&B1[r0 + 1][e],
                      *(const float4*)&B1[r0 + 2][e], *(const float4*)&B1[r0 + 3][e],
                      *(const float4*)&B4[c0 + 0][e], *(const float4*)&B4[c0 + 1][e],
                      *(const float4*)&B4[c0 + 2][e], *(const float4*)&B4[c0 + 3][e]);
            #pragma unroll
            for (int a = 0; a < 4; a++)
                *(float4*)&B2[r0 + a][c0] = make_float4(acc[a][0], acc[a][1], acc[a][2], acc[a][3]);

            if (t < DD) {               // qk = Wq@bk
                float u = 0.f;
                for (int e = 0; e < DD; e++) u += B1[t][e] * bkS[e];
                qkS[t] = u;
            } else if (t < 2 * DD) {    // kq = Wk@bq
                const int rr = t - DD;
                float u = 0.f;
                for (int e = 0; e < DD; e++) u += B4[rr][e] * bqS[e];
                kqS[rr] = u;
            } else if (t == 2 * DD) {   // qbk = bq.bk
                float u = 0.f;
                for (int e = 0; e < DD; e++) u += bqS[e] * bkS[e];
                qbkS[0] = u;
            }
        }
        __syncthreads();                // B4 (Wk) free; B1 free
        for (int i2 = t; i2 < DD * DD; i2 += NT)
            B4[i2 >> 6][i2 & 63] = Acc<T>::ld(blkw, wOff + i2);   // Wb

        // ---- F: wait 65 combine flags; stage T' = T'raw + s.bv^T -> B3;
        //      load su directly (su phase deleted) ----
        {
            if (t < 65) pollw(&cflag[bb * NCH + t], ep);
            __syncthreads();            // Wb staging + T'/s/su visible
            #pragma unroll
            for (int a = 0; a < 4; a++) {
                float4 v = *(const float4*)&GgL[(r0 + a) * DD + c0];
                const float sv = GgL[4096 + r0 + a];
                v.x += sv * bvS[c0 + 0];
                v.y += sv * bvS[c0 + 1];
                v.z += sv * bvS[c0 + 2];
                v.w += sv * bvS[c0 + 3];
                *(float4*)&B3[r0 + a][c0] = v;
            }
            if (t < DD) suS[t] = GgL[4160 + t];
            __syncthreads();
        }

        // ---- H: weff = Wb + C0*(A@T' + qk su^T) -> B5 ; beff ----
        {
            float acc[4][4];
            #pragma unroll
            for (int a = 0; a < 4; a++)
                #pragma unroll
                for (int b = 0; b < 4; b++) acc[a][b] = qkS[r0 + a] * suS[c0 + b];
            #pragma unroll 2
            for (int e = 0; e < DD; e += 4)
                mm4x4(acc,
                      *(const float4*)&B2[r0 + 0][e], *(const float4*)&B2[r0 + 1][e],
                      *(const float4*)&B2[r0 + 2][e], *(const float4*)&B2[r0 + 3][e],
                      *(const float4*)&B3[e + 0][c0], *(const float4*)&B3[e + 1][c0],
                      *(const float4*)&B3[e + 2][c0], *(const float4*)&B3[e + 3][c0]);
            #pragma unroll
            for (int a = 0; a < 4; a++) {
                float4 w;
                w.x = B4[r0 + a][c0 + 0] + C0F * acc[a][0];
                w.y = B4[r0 + a][c0 + 1] + C0F * acc[a][1];
                w.z = B4[r0 + a][c0 + 2] + C0F * acc[a][2];
                w.w = B4[r0 + a][c0 + 3] + C0F * acc[a][3];
                *(float4*)&B5[r0 + a][c0] = w;      // B5 (Wv) dead after combine
            }
            {   // beff partials: kq . T' (reads B3 only)
                const int c = t & 63, q = t >> 6;
                float u = 0.f;
                #pragma unroll
                for (int e2 = 0; e2 < 16; e2++) u += kqS[q * 16 + e2] * B3[q * 16 + e2][c];
                red[q][c] = u;
            }
            __syncthreads();            // red + weff visible
            if (t < DD) beS[t] = Acc<T>::ld(blkb, bOff + t)
                               + C0F * (red[0][t] + red[1][t] + red[2][t] + red[3][t]
                                        + qbkS[0] * suS[t]);
        }
        __syncthreads();

        // ---- apply: h' = gelu(h@weff + beff) on resident rows ----
        float o[2][4];
        #pragma unroll
        for (int a = 0; a < 2; a++) {
            const int row = r + 16 * a;
            float acc2[4];
            #pragma unroll
            for (int b = 0; b < 4; b++) acc2[b] = beS[c4 + b];
            for (int d = 0; d < DD; d++) {
                float hv = sH[row][d];
                float4 w4 = *(const float4*)&B5[d][c4];
                acc2[0] += hv * w4.x; acc2[1] += hv * w4.y;
                acc2[2] += hv * w4.z; acc2[3] += hv * w4.w;
            }
            #pragma unroll
            for (int b = 0; b < 4; b++) o[a][b] = gelu_exact(acc2[b]);
        }

        if (layer == NLAYER - 1) {
            float pbv = Acc<T>::ld(pb, 0);
            #pragma unroll
            for (int a = 0; a < 2; a++) {
                float p = 0.f;
                #pragma unroll
                for (int b = 0; b < 4; b++) p += o[a][b] * Acc<T>::ld(pw, c4 + b);
                p += __shfl_xor(p, 1);
                p += __shfl_xor(p, 2);
                p += __shfl_xor(p, 4);
                p += __shfl_xor(p, 8);
                if ((t & 15) == 0) Acc<T>::st(out, row0 + r + 16 * a, p + pbv);
            }
        } else {
            __syncthreads();    // weff/beS/sH reads done before sH overwrite
            #pragma unroll
            for (int a = 0; a < 2; a++)
                *(float4*)&sH[r + 16 * a][c4] =
                    make_float4(o[a][0], o[a][1], o[a][2], o[a][3]);
            __syncthreads();
        }
    }
}

__global__ __launch_bounds__(NT) void gno_kernel(
    const void* x, const void* lw, const void* lb,
    const void* blkw, const void* blkb,
    const void* qw, const void* qb, const void* kw, const void* kb,
    const void* vw, const void* vb, const void* pw, const void* pb,
    void* out, float* Gpart, float* Gg, unsigned* bar, int mode)
{
    __shared__ alignas(16) float smem[SM_TOT];   // 99072 B
    __shared__ int stot;

    const int blk = blockIdx.x, t = threadIdx.x;

    bool isbf;
    if (mode >= 0) {
        isbf = (mode == 1);
    } else {
        // fallback: device dtype scan (same result in every block)
        if (t == 0) stot = 0;
        __syncthreads();
        int cdt = 0;
        const unsigned int* xw = (const unsigned int*)x;
        for (int i = t; i < 8192; i += NT) {
            unsigned u = xw[i] & 0xFFFFu;
            int e = (u >> 7) & 0xFF;
            cdt += (u == 0u || (e >= 100 && e <= 142)) ? 1 : 0;
        }
        atomicAdd(&stot, cdt);
        __syncthreads();
        isbf = (stot > 4915);
    }

    unsigned* aflag = bar;          // [256] producer epochs
    unsigned* cflag = bar + 256;    // [256] combine epochs (65 used per batch)

    if (isbf)
        run_net<bf16>(x, lw, lb, blkw, blkb, qw, qb, kw, kb, vw, vb, pw, pb,
                      out, Gpart, Gg, aflag, cflag, smem, blk, t);
    else
        run_net<float>(x, lw, lb, blkw, blkb, qw, qb, kw, kb, vw, vb, pw, pb,
                       out, Gpart, Gg, aflag, cflag, smem, blk, t);
}

extern "C" void kernel_launch(void* const* d_in, const int* in_sizes, int n_in,
                              void* d_out, int out_size, void* d_ws, size_t ws_size,
                              hipStream_t stream)
{
    const void* x    = d_in[0];
    const void* lw   = d_in[1];
    const void* lb   = d_in[2];
    const void* blkw = d_in[3];
    const void* blkb = d_in[4];
    const void* qw   = d_in[5];
    const void* qb   = d_in[6];
    const void* kw   = d_in[7];
    const void* kb   = d_in[8];
    const void* vw   = d_in[9];
    const void* vb   = d_in[10];
    const void* pw   = d_in[11];
    const void* pb   = d_in[12];

    // x = [2,64,64,3]: fp32 -> 98304 B, bf16 -> 49152 B
    int mode = -1;
    if (in_sizes && n_in > 0) {
        if (in_sizes[0] == 49152) mode = 1;
        else if (in_sizes[0] == 98304) mode = 0;
    }

    unsigned* bar = (unsigned*)d_ws;                      // [512] flag words
    float* Gpart  = (float*)d_ws + 512;                   // [256][4160] 4.26 MB
    float* Gg     = Gpart + (size_t)NBLK * PSZ;           // [4][2][4224] T'raw+s+su

    (void)hipMemsetAsync(bar, 0, 512 * sizeof(unsigned), stream);
    gno_kernel<<<NBLK, NT, 0, stream>>>(x, lw, lb, blkw, blkb, qw, qb, kw, kb,
                                        vw, vb, pw, pb, d_out, Gpart, Gg, bar, mode);
}